// Round 13
// baseline (327.569 us; speedup 1.0000x reference)
//
#include <hip/hip_runtime.h>
#include <hip/hip_fp16.h>

typedef _Float16 half8 __attribute__((ext_vector_type(8)));
typedef float f32x4 __attribute__((ext_vector_type(4)));
typedef long lng2 __attribute__((ext_vector_type(2)));

#define B_   4
#define L_   4096
#define D_   128
#define M_   (B_*L_)     // 16384
#define D2_  256
#define H_   512
#define OUT_ 55

__device__ __forceinline__ f32x4 mfma16(half8 a, half8 b, f32x4 c) {
    return __builtin_amdgcn_mfma_f32_16x16x32_f16(a, b, c, 0, 0, 0);
}
__device__ __forceinline__ f32x4 mfma8(long a, long b, f32x4 c) {
    return __builtin_amdgcn_mfma_f32_16x16x32_fp8_fp8(a, b, c, 0, 0, 0);
}
// pack 4 floats -> 4 fp8 e4m3 bytes (OCP on gfx950)
__device__ __forceinline__ int pk4(float a, float b, float c, float d) {
    int t = __builtin_amdgcn_cvt_pk_fp8_f32(a, b, 0, false);
    return __builtin_amdgcn_cvt_pk_fp8_f32(c, d, t, true);
}
// raw v_exp_f32 — exp2f w/o fast-math lowers to OCML denorm-safe seq (~25cyc, r8 VALUBusy=47%)
__device__ __forceinline__ float fexp2(float x) { return __builtin_amdgcn_exp2f(x); }

// fold softmax scale (1/sqrt(128)) * log2(e) into k2 so score uses bare v_exp
#define KSCL (0.08838834764831845f * 1.4426950408889634f)

// ---- weight swizzle offsets (in halfs) within wsw region ----
#define WQ_OFF   0
#define WV1_OFF  16384
#define WK_OFF   32768
#define WV2_OFF  49152
#define WP1_OFF  65536
#define WP2_OFF  81920
#define WF1_OFF  98304     // 256x512 = 131072
#define WF2_OFF  229376    // 512x256 = 131072
#define WO_OFF   360448    // 256x64 (padded) = 16384

// Permuted k-map (within a 32-k chunk): k5 = (h<4 ? q*4+h : 16+q*4+(h-4)).
// Used for fp8 P & V and fp16 att & Wp1/Wp2 — A/B agree pairwise.

// Pre-swizzle weights (fp32 row-major [K][N]) into B-fragment layout fp16.
// canonical: q=(k>>3)&3, j=k&7 ; permK (Wp1/Wp2 only): q=(k>>2)&3, j=(k&3)+4*((k>>4)&1)
__global__ void prep_kernel(const float* Wq, const float* Wv1, const float* Wk,
                            const float* Wv2, const float* Wp1, const float* Wp2,
                            const float* Wf1, const float* Wf2, const float* Wo,
                            _Float16* wsw) {
    int id = blockIdx.y;
    int t  = blockIdx.x * 256 + threadIdx.x;
    const float* src = nullptr; int K = 0, N = 0, Npad = 0, off = 0;
    switch (id) {
        case 0: src = Wq;  K = 128; N = 128; Npad = 128; off = WQ_OFF;  break;
        case 1: src = Wv1; K = 128; N = 128; Npad = 128; off = WV1_OFF; break;
        case 2: src = Wk;  K = 128; N = 128; Npad = 128; off = WK_OFF;  break;
        case 3: src = Wv2; K = 128; N = 128; Npad = 128; off = WV2_OFF; break;
        case 4: src = Wp1; K = 128; N = 128; Npad = 128; off = WP1_OFF; break;
        case 5: src = Wp2; K = 128; N = 128; Npad = 128; off = WP2_OFF; break;
        case 6: src = Wf1; K = 256; N = 512; Npad = 512; off = WF1_OFF; break;
        case 7: src = Wf2; K = 512; N = 256; Npad = 256; off = WF2_OFF; break;
        case 8: src = Wo;  K = 256; N = 55;  Npad = 64;  off = WO_OFF;  break;
        default: return;
    }
    int total = K * Npad;
    if (t >= total) return;
    int k = t / Npad, n = t % Npad;
    float v = (n < N) ? src[k * N + n] : 0.f;
    int s = k >> 5, c = n >> 4, ln = n & 15;
    int q, j;
    if (id == 4 || id == 5) { q = (k >> 2) & 3; j = (k & 3) + (((k >> 4) & 1) << 2); }
    else                    { q = (k >> 3) & 3; j = k & 7; }
    int nc = Npad >> 4;
    wsw[off + ((size_t)((s * nc + c) * 64 + q * 16 + ln)) * 8 + j] = (_Float16)v;
}

// FR layout for X[M][C] halfs:
// idx = ((lt*(C/32) + s)*64 + q*16 + ln_r)*8 + j ; lt=row>>4, ln_r=row&15,
// s=col>>5, q=(col>>3)&3, j=col&7.

// LayerNorm over D=128, one wave per token, fp32 in -> fp16 FR-swizzled out
__global__ __launch_bounds__(256) void ln_kernel(const float* x1, const float* x2,
        const float* g1, const float* b1, const float* g2, const float* b2,
        _Float16* x1n, _Float16* x2n) {
    int wave = threadIdx.x >> 6, lane = threadIdx.x & 63;
    int token = blockIdx.x * 4 + wave;
    const float* x = blockIdx.y ? x2 : x1;
    const float* g = blockIdx.y ? g2 : g1;
    const float* bb = blockIdx.y ? b2 : b1;
    _Float16* o = blockIdx.y ? x2n : x1n;
    const float* xr = x + (size_t)token * D_;
    float a0 = xr[lane], a1 = xr[lane + 64];
    float s = a0 + a1, s2 = a0 * a0 + a1 * a1;
    #pragma unroll
    for (int off = 1; off < 64; off <<= 1) {
        s += __shfl_xor(s, off);
        s2 += __shfl_xor(s2, off);
    }
    float mean = s * (1.f / 128.f);
    float var = s2 * (1.f / 128.f) - mean * mean;
    float inv = rsqrtf(var + 1e-5f);
    int lt = token >> 4, ln_r = token & 15;
    #pragma unroll
    for (int h = 0; h < 2; h++) {
        int col = lane + h * 64;
        float v = (h ? a1 : a0);
        float out = (v - mean) * inv * g[col] + bb[col];
        int ss = col >> 5, q = (col >> 3) & 3, j = col & 7;
        o[((size_t)((lt * 4 + ss) * 64 + q * 16 + ln_r)) * 8 + j] = (_Float16)out;
    }
}

// Projections. q1 fp16 FR; k2 fp16 FR pre-scaled by KSCL; v1/v2 -> vsw8 fp8
// permuted-k B-frag layout. W-frag register prefetch pipeline over c.
__global__ __launch_bounds__(256) void proj_kernel(const _Float16* x1n, const _Float16* x2n,
        const _Float16* wsw, const float* bq, const float* bv1, const float* bk,
        const float* bv2, _Float16* q1, _Float16* k2, unsigned char* vsw8) {
    int g = blockIdx.y;   // 0:Wq 1:Wv1 2:Wk 3:Wv2
    const _Float16* A = (g < 2) ? x1n : x2n;
    const _Float16* Bw = wsw + g * 16384;
    const float* bias = (g == 0) ? bq : (g == 1) ? bv1 : (g == 2) ? bk : bv2;
    int wave = threadIdx.x >> 6, lane = threadIdx.x & 63;
    int quad = lane >> 4, ln = lane & 15;
    int mbase = blockIdx.x * 64 + wave * 16;
    int lt = mbase >> 4;

    half8 a[4];
    #pragma unroll
    for (int s = 0; s < 4; s++)
        a[s] = *(const half8*)(A + ((size_t)((lt * 4 + s) * 64 + lane)) * 8);

    f32x4 acc[8];
    #pragma unroll
    for (int c = 0; c < 8; c++) acc[c] = f32x4{0.f, 0.f, 0.f, 0.f};

    half8 Wc[4], Wn[4];
    #pragma unroll
    for (int s = 0; s < 4; s++)
        Wc[s] = *(const half8*)(Bw + ((size_t)((s * 8 + 0) * 64 + lane)) * 8);
    #pragma unroll
    for (int c = 0; c < 8; c++) {
        int cn = (c < 7) ? c + 1 : 7;
        #pragma unroll
        for (int s = 0; s < 4; s++)
            Wn[s] = *(const half8*)(Bw + ((size_t)((s * 8 + cn) * 64 + lane)) * 8);
        #pragma unroll
        for (int s = 0; s < 4; s++)
            acc[c] = mfma16(a[s], Wc[s], acc[c]);
        #pragma unroll
        for (int s = 0; s < 4; s++) Wc[s] = Wn[s];
    }

    bool isV = (g == 1) || (g == 3);
    if (!isV) {
        float scl = (g == 2) ? KSCL : 1.f;
        _Float16* out = (g == 0) ? q1 : k2;
        #pragma unroll
        for (int c = 0; c < 8; c++) {
            int n = c * 16 + ln;
            float bv = bias[n];
            #pragma unroll
            for (int r = 0; r < 4; r++) {
                int s_o = c >> 1, q_o = ((c & 1) << 1) | (ln >> 3), j = ln & 7;
                out[((size_t)((lt * 4 + s_o) * 64 + q_o * 16 + (quad * 4 + r))) * 8 + j]
                    = (_Float16)((acc[c][r] + bv) * scl);
            }
        }
    } else {
        int cbase = (g == 3) ? 8 : 0;
        int b = mbase >> 12;
        int l0 = (mbase & (L_ - 1)) + quad * 4;
        int sp = l0 >> 6, tt = (l0 >> 4) & 3, q2 = (l0 >> 2) & 3;
        unsigned char* Vb = vsw8 + (size_t)b * (1u << 20);
        #pragma unroll
        for (int c = 0; c < 8; c++) {
            int n = c * 16 + ln;
            float bv = bias[n];
            int pk = pk4(acc[c][0] + bv, acc[c][1] + bv, acc[c][2] + bv, acc[c][3] + bv);
            *(int*)(Vb + (((size_t)(sp * 16 + cbase + c) * 64 + q2 * 16 + ln) * 16 + tt * 4)) = pk;
        }
    }
}

// FUSED attention: S^T -> exp -> fp8 P in LDS -> O^T = V^T.P^T, per 16-row
// m-tile. 1024 blocks x 8 waves. 2 k-passes of 2048 (P-LDS 32 KB/pass).
// score: wave w owns k-slice [w*256,+256) of the pass (P int4/lane -> LDS,
// zero transpose — r7 permuted-k algebra). PV: wave w owns V-cols [w*32,+32),
// reads all P of the pass from LDS. Rowsum in-block (no atomics, no pmat8).
__global__ __launch_bounds__(512) void flash2_kernel(
        const _Float16* __restrict__ q1sw, const _Float16* __restrict__ k2sw,
        const unsigned char* __restrict__ vsw8,
        _Float16* __restrict__ att1, _Float16* __restrict__ att2) {
    __shared__ int4 Pl[32 * 64];     // 32 KB: P for one pass (2048 k x 16 m)
    __shared__ float rsf[8][16];
    int w = threadIdx.x >> 6, lane = threadIdx.x & 63;
    int ln = lane & 15;
    int mt = blockIdx.x;             // global 16-row m-tile
    int b = mt >> 8;
    const unsigned char* Vb = vsw8 + (size_t)b * (1u << 20);

    // k2 B-frags for our 16 att rows (loop-invariant)
    half8 bq[4];
    #pragma unroll
    for (int s = 0; s < 4; s++)
        bq[s] = *(const half8*)(k2sw + ((size_t)((mt * 4 + s) * 64 + lane)) * 8);

    f32x4 oacc[2];
    oacc[0] = f32x4{0.f, 0.f, 0.f, 0.f};
    oacc[1] = f32x4{0.f, 0.f, 0.f, 0.f};
    float rs = 0.f;
    int ct0 = w * 2;                 // V n-tiles for PV phase

    #pragma unroll
    for (int pass = 0; pass < 2; pass++) {
        int k0p = pass * 2048;
        // ---- score phase: 4 k-blocks of 64 ----
        #pragma unroll
        for (int kb = 0; kb < 4; kb++) {
            int kg = k0p + w * 256 + kb * 64;
            int ltk = ((b << 12) + kg) >> 4;
            int4 d;
            #pragma unroll
            for (int i = 0; i < 4; i++) {
                f32x4 sa = f32x4{0.f, 0.f, 0.f, 0.f};
                #pragma unroll
                for (int s = 0; s < 4; s++) {
                    half8 aq = *(const half8*)(q1sw
                        + ((size_t)(((ltk + i) * 4 + s) * 64 + lane)) * 8);
                    sa = mfma16(aq, bq[s], sa);
                }
                float p0 = fexp2(sa[0]);
                float p1 = fexp2(sa[1]);
                float p2 = fexp2(sa[2]);
                float p3 = fexp2(sa[3]);
                rs += (p0 + p1) + (p2 + p3);
                ((int*)&d)[i] = pk4(p0, p1, p2, p3);
            }
            Pl[(w * 4 + kb) * 64 + lane] = d;
        }
        if (pass == 1) {
            // finalize rowsum partial (sum quads) and publish
            float t = rs;
            t += __shfl_xor(t, 16);
            t += __shfl_xor(t, 32);
            if (lane < 16) rsf[w][ln] = t;
        }
        __syncthreads();

        // ---- PV phase: all 32 k-blocks of the pass, our 32 V-cols ----
        int spb = k0p >> 6;
        lng2 V0c = *(const lng2*)(Vb + ((size_t)((spb * 16 + ct0) * 64 + lane)) * 16);
        lng2 V1c = *(const lng2*)(Vb + ((size_t)((spb * 16 + ct0 + 1) * 64 + lane)) * 16);
        for (int kb = 0; kb < 32; kb++) {
            int spn = spb + ((kb < 31) ? kb + 1 : 31);
            lng2 V0n = *(const lng2*)(Vb + ((size_t)((spn * 16 + ct0) * 64 + lane)) * 16);
            lng2 V1n = *(const lng2*)(Vb + ((size_t)((spn * 16 + ct0 + 1) * 64 + lane)) * 16);
            lng2 Pf = *(const lng2*)&Pl[kb * 64 + lane];
            oacc[0] = mfma8(V0c.x, Pf.x, oacc[0]);
            oacc[0] = mfma8(V0c.y, Pf.y, oacc[0]);
            oacc[1] = mfma8(V1c.x, Pf.x, oacc[1]);
            oacc[1] = mfma8(V1c.y, Pf.y, oacc[1]);
            V0c = V0n; V1c = V1n;
        }
        if (pass == 0) __syncthreads();   // protect Pl before pass-1 overwrite
    }

    // ---- epilogue: combine rowsums, normalize, FR store ----
    float tot = 0.f;
    #pragma unroll
    for (int k = 0; k < 8; k++) tot += rsf[k][ln];
    float inv = 1.f / tot;
    half8 v;
    #pragma unroll
    for (int r = 0; r < 4; r++) {
        v[r]     = (_Float16)(oacc[0][r] * inv);
        v[r + 4] = (_Float16)(oacc[1][r] * inv);
    }
    _Float16* att = (w < 4) ? att1 : att2;
    *(half8*)(att + ((size_t)((mt * 4 + (w & 3)) * 64 + lane)) * 8) = v;
}

// out_s = att_s @ Wp_s + bias + residual ; concat -> res (fp16) ; LNf -> xn (FR fp16)
// 512 blocks x (2 rowtiles x 2 streams).
__global__ __launch_bounds__(256) void attn_out_kernel(const _Float16* att1, const _Float16* att2,
        const _Float16* wsw, const float* bp1, const float* bp2,
        const float* x1, const float* x2, const float* lnf_g, const float* lnf_b,
        _Float16* res, _Float16* xn) {
    __shared__ float sst[2][16][2][2];
    int w = threadIdx.x >> 6, lane = threadIdx.x & 63;
    int quad = lane >> 4, ln = lane & 15;
    int rt = w & 1, st = w >> 1;
    int mbase = blockIdx.x * 32 + rt * 16;
    int lt = mbase >> 4;
    const _Float16* att = st ? att2 : att1;
    const _Float16* Wp = wsw + (st ? WP2_OFF : WP1_OFF);
    const float* bp = st ? bp2 : bp1;
    const float* xres = st ? x2 : x1;

    half8 a[4];
    #pragma unroll
    for (int s = 0; s < 4; s++)
        a[s] = *(const half8*)(att + ((size_t)((lt * 4 + s) * 64 + lane)) * 8);

    f32x4 y[8];
    #pragma unroll
    for (int c = 0; c < 8; c++) y[c] = f32x4{0,0,0,0};

    half8 Wc[4], Wn[4];
    #pragma unroll
    for (int s = 0; s < 4; s++)
        Wc[s] = *(const half8*)(Wp + ((size_t)((s * 8 + 0) * 64 + lane)) * 8);
    #pragma unroll
    for (int c = 0; c < 8; c++) {
        int cn = (c < 7) ? c + 1 : 7;
        #pragma unroll
        for (int s = 0; s < 4; s++)
            Wn[s] = *(const half8*)(Wp + ((size_t)((s * 8 + cn) * 64 + lane)) * 8);
        #pragma unroll
        for (int s = 0; s < 4; s++)
            y[c] = mfma16(a[s], Wc[s], y[c]);
        #pragma unroll
        for (int s = 0; s < 4; s++) Wc[s] = Wn[s];
    }

    float psum[4] = {0,0,0,0}, psq[4] = {0,0,0,0};
    #pragma unroll
    for (int c = 0; c < 8; c++) {
        int n = c * 16 + ln;
        float bv = bp[n];
        #pragma unroll
        for (int r = 0; r < 4; r++) {
            int m = mbase + quad * 4 + r;
            float v = y[c][r] + bv + xres[(size_t)m * D_ + n];
            y[c][r] = v; psum[r] += v; psq[r] += v * v;
        }
    }
    #pragma unroll
    for (int off = 1; off < 16; off <<= 1)
        #pragma unroll
        for (int r = 0; r < 4; r++) { psum[r] += __shfl_xor(psum[r], off); psq[r] += __shfl_xor(psq[r], off); }
    if (ln == 0)
        #pragma unroll
        for (int r = 0; r < 4; r++) {
            sst[rt][quad * 4 + r][st][0] = psum[r];
            sst[rt][quad * 4 + r][st][1] = psq[r];
        }
    __syncthreads();
    #pragma unroll
    for (int r = 0; r < 4; r++) {
        float su = sst[rt][quad * 4 + r][0][0] + sst[rt][quad * 4 + r][1][0];
        float sq = sst[rt][quad * 4 + r][0][1] + sst[rt][quad * 4 + r][1][1];
        float mean = su * (1.f / 256.f);
        float var = sq * (1.f / 256.f) - mean * mean;
        float inv = rsqrtf(var + 1e-5f);
        int m = mbase + quad * 4 + r;
        int lt_m = m >> 4;
        #pragma unroll
        for (int c = 0; c < 8; c++) {
            int colg = st * 128 + c * 16 + ln;
            res[(size_t)m * D2_ + colg] = (_Float16)y[c][r];
            float yn = (y[c][r] - mean) * inv * lnf_g[colg] + lnf_b[colg];
            int s_x = colg >> 5, q_x = (colg >> 3) & 3, j = colg & 7;
            xn[((size_t)((lt_m * 8 + s_x) * 64 + q_x * 16 + (m & 15))) * 8 + j] = (_Float16)yn;
        }
    }
}

// h = gelu(xn @ Wf1 + bf1)  [M x 512], FR in/out. W-prefetch pipeline; fast
// tanh-form GELU (x*sigmoid(2u)) via raw v_exp.
__global__ __launch_bounds__(256) void ffn1_kernel(const _Float16* xn, const _Float16* wsw,
        const float* bf1, _Float16* h) {
    int wave = threadIdx.x >> 6, lane = threadIdx.x & 63;
    int quad = lane >> 4, ln = lane & 15;
    int mbase = blockIdx.x * 64 + wave * 16;
    int lt = mbase >> 4;
    int nt = blockIdx.y;   // 0..3
    const _Float16* W = wsw + WF1_OFF;   // K=256, N=512, nc=32

    half8 a[8];
    #pragma unroll
    for (int s = 0; s < 8; s++)
        a[s] = *(const half8*)(xn + ((size_t)((lt * 8 + s) * 64 + lane)) * 8);

    f32x4 acc[8];
    #pragma unroll
    for (int c = 0; c < 8; c++) acc[c] = f32x4{0,0,0,0};

    half8 Wc[8], Wn[8];
    #pragma unroll
    for (int s = 0; s < 8; s++)
        Wc[s] = *(const half8*)(W + ((size_t)((s * 32 + nt * 8) * 64 + lane)) * 8);
    #pragma unroll
    for (int c = 0; c < 8; c++) {
        int cn = (c < 7) ? c + 1 : 7;
        #pragma unroll
        for (int s = 0; s < 8; s++)
            Wn[s] = *(const half8*)(W + ((size_t)((s * 32 + nt * 8 + cn) * 64 + lane)) * 8);
        #pragma unroll
        for (int s = 0; s < 8; s++)
            acc[c] = mfma16(a[s], Wc[s], acc[c]);
        #pragma unroll
        for (int s = 0; s < 8; s++) Wc[s] = Wn[s];
    }
    #pragma unroll
    for (int c = 0; c < 8; c++) {
        int n = nt * 128 + c * 16 + ln;
        float bv = bf1[n];
        int s_h = n >> 5, q_h = (n >> 3) & 3, j = n & 7;
        #pragma unroll
        for (int r = 0; r < 4; r++) {
            float v = acc[c][r] + bv;
            float u = 0.7978845608f * (v + 0.044715f * v * v * v);
            float e = fexp2(-2.8853900818f * u);     // 2*log2(e)*u
            float ge = v * __builtin_amdgcn_rcpf(1.f + e);
            h[((size_t)((lt * 16 + s_h) * 64 + q_h * 16 + (quad * 4 + r))) * 8 + j] = (_Float16)ge;
        }
    }
}

// FUSED: xn2 = LN3(h @ Wf2 + bf2 + res) -> LDS tile ; out = xn2 @ Wo + bo.
__global__ __launch_bounds__(256) void ffn2_out_kernel(const _Float16* h, const _Float16* wsw,
        const float* bf2, const _Float16* res, const float* g3, const float* b3,
        const float* bo, float* out) {
    __shared__ float sst[2][16][2][2];
    __shared__ _Float16 xt[8192];        // 16 KB: 32 rows x 256 cols, FR layout
    __shared__ f32x4 pc[2][4][64];       // 8 KB: out k-half partials
    int w = threadIdx.x >> 6, lane = threadIdx.x & 63;
    int quad = lane >> 4, ln = lane & 15;
    int rt = w & 1, nh = w >> 1;
    int mb = blockIdx.x * 32 + rt * 16;
    int lt = mb >> 4;
    const _Float16* W = wsw + WF2_OFF;   // K=512, N=256, nc=16

    f32x4 acc[8];
    #pragma unroll
    for (int c = 0; c < 8; c++) acc[c] = f32x4{0,0,0,0};

    half8 aC, aN;
    half8 Wc[8], Wn[8];
    aC = *(const half8*)(h + ((size_t)((lt * 16 + 0) * 64 + lane)) * 8);
    #pragma unroll
    for (int c = 0; c < 8; c++)
        Wc[c] = *(const half8*)(W + ((size_t)((0 * 16 + nh * 8 + c) * 64 + lane)) * 8);

    #pragma unroll
    for (int s = 0; s < 16; s++) {
        int sn = (s < 15) ? s + 1 : 15;
        aN = *(const half8*)(h + ((size_t)((lt * 16 + sn) * 64 + lane)) * 8);
        #pragma unroll
        for (int c = 0; c < 8; c++)
            Wn[c] = *(const half8*)(W + ((size_t)((sn * 16 + nh * 8 + c) * 64 + lane)) * 8);
        #pragma unroll
        for (int c = 0; c < 8; c++)
            acc[c] = mfma16(aC, Wc[c], acc[c]);
        aC = aN;
        #pragma unroll
        for (int c = 0; c < 8; c++) Wc[c] = Wn[c];
    }

    float y[8][4];
    float psum[4] = {0,0,0,0}, psq[4] = {0,0,0,0};
    #pragma unroll
    for (int c = 0; c < 8; c++) {
        int n = nh * 128 + c * 16 + ln;
        float bv = bf2[n];
        #pragma unroll
        for (int r = 0; r < 4; r++) {
            int m = mb + quad * 4 + r;
            float v = acc[c][r] + bv + (float)res[(size_t)m * D2_ + n];
            y[c][r] = v; psum[r] += v; psq[r] += v * v;
        }
    }
    #pragma unroll
    for (int off = 1; off < 16; off <<= 1)
        #pragma unroll
        for (int r = 0; r < 4; r++) { psum[r] += __shfl_xor(psum[r], off); psq[r] += __shfl_xor(psq[r], off); }
    if (ln == 0)
        #pragma unroll
        for (int r = 0; r < 4; r++) { sst[rt][quad * 4 + r][nh][0] = psum[r]; sst[rt][quad * 4 + r][nh][1] = psq[r]; }
    __syncthreads();
    #pragma unroll
    for (int r = 0; r < 4; r++) {
        float su = sst[rt][quad * 4 + r][0][0] + sst[rt][quad * 4 + r][1][0];
        float sq = sst[rt][quad * 4 + r][0][1] + sst[rt][quad * 4 + r][1][1];
        float mean = su * (1.f / 256.f);
        float var = sq * (1.f / 256.f) - mean * mean;
        float invs = rsqrtf(var + 1e-5f);
        #pragma unroll
        for (int c = 0; c < 8; c++) {
            int n = nh * 128 + c * 16 + ln;
            float yn = (y[c][r] - mean) * invs * g3[n] + b3[n];
            int s_x = n >> 5, q_x = (n >> 3) & 3, j = n & 7;
            xt[((rt * 8 + s_x) * 64 + q_x * 16 + (quad * 4 + r)) * 8 + j] = (_Float16)yn;
        }
    }
    __syncthreads();

    // ---- out phase: waves (rt2, kh) ----
    int rt2 = w & 1, kh = w >> 1;
    const _Float16* Wo = wsw + WO_OFF;   // K=256, N=64(padded), nc=4
    f32x4 oacc[4];
    #pragma unroll
    for (int c = 0; c < 4; c++) oacc[c] = f32x4{0,0,0,0};
    #pragma unroll
    for (int ss = 0; ss < 4; ss++) {
        int s = kh * 4 + ss;
        half8 a = *(const half8*)(xt + ((size_t)((rt2 * 8 + s) * 64 + lane)) * 8);
        #pragma unroll
        for (int c = 0; c < 4; c++)
            oacc[c] = mfma16(a, *(const half8*)(Wo + ((size_t)((s * 4 + c) * 64 + lane)) * 8), oacc[c]);
    }
    if (kh == 1)
        #pragma unroll
        for (int c = 0; c < 4; c++) pc[rt2][c][lane] = oacc[c];
    __syncthreads();
    if (kh == 0) {
        int mb2 = blockIdx.x * 32 + rt2 * 16;
        #pragma unroll
        for (int c = 0; c < 4; c++) {
            f32x4 p = pc[rt2][c][lane];
            int n = c * 16 + ln;
            if (n < OUT_) {
                float bv = bo[n];
                #pragma unroll
                for (int r = 0; r < 4; r++)
                    out[(size_t)(mb2 + quad * 4 + r) * OUT_ + n] = oacc[c][r] + p[r] + bv;
            }
        }
    }
}

extern "C" void kernel_launch(void* const* d_in, const int* in_sizes, int n_in,
                              void* d_out, int out_size, void* d_ws, size_t ws_size,
                              hipStream_t stream) {
    const float* x1    = (const float*)d_in[0];
    const float* x2    = (const float*)d_in[1];
    const float* ln1_g = (const float*)d_in[2];
    const float* ln1_b = (const float*)d_in[3];
    const float* ln2_g = (const float*)d_in[4];
    const float* ln2_b = (const float*)d_in[5];
    const float* Wq    = (const float*)d_in[6];
    const float* bq    = (const float*)d_in[7];
    const float* Wv1   = (const float*)d_in[8];
    const float* bv1   = (const float*)d_in[9];
    const float* Wk    = (const float*)d_in[10];
    const float* bk    = (const float*)d_in[11];
    const float* Wv2   = (const float*)d_in[12];
    const float* bv2   = (const float*)d_in[13];
    const float* Wp1   = (const float*)d_in[14];
    const float* bp1   = (const float*)d_in[15];
    const float* Wp2   = (const float*)d_in[16];
    const float* bp2   = (const float*)d_in[17];
    const float* lnf_g = (const float*)d_in[18];
    const float* lnf_b = (const float*)d_in[19];
    const float* Wf1   = (const float*)d_in[20];
    const float* bf1   = (const float*)d_in[21];
    const float* Wf2   = (const float*)d_in[22];
    const float* bf2   = (const float*)d_in[23];
    const float* ln3_g = (const float*)d_in[24];
    const float* ln3_b = (const float*)d_in[25];
    const float* Wo    = (const float*)d_in[26];
    const float* bo    = (const float*)d_in[27];
    float* out = (float*)d_out;

    char* ws = (char*)d_ws;
    const size_t MB = 1 << 20;
    _Float16* q1sw   = (_Float16*)(ws + 0 * MB);    // 4 MB
    _Float16* k2sw   = (_Float16*)(ws + 4 * MB);    // 4 MB
    unsigned char* vsw8 = (unsigned char*)(ws + 8 * MB);   // 4 MB (fp8 Vcat per batch)
    _Float16* att1   = (_Float16*)(ws + 12 * MB);   // 4 MB
    _Float16* att2   = (_Float16*)(ws + 16 * MB);   // 4 MB
    _Float16* x1n    = (_Float16*)(ws + 20 * MB);   // 4 MB
    _Float16* x2n    = (_Float16*)(ws + 24 * MB);   // 4 MB
    _Float16* wsw    = (_Float16*)(ws + 28 * MB);   // ~0.74 MB
    _Float16* res    = (_Float16*)(ws + 30 * MB);   // 8 MB
    _Float16* xn     = (_Float16*)(ws + 46 * MB);   // 8 MB
    _Float16* h      = (_Float16*)(ws + 54 * MB);   // 16 MB

    prep_kernel<<<dim3(512, 9), 256, 0, stream>>>(Wq, Wv1, Wk, Wv2, Wp1, Wp2, Wf1, Wf2, Wo, wsw);
    ln_kernel<<<dim3(M_ / 4, 2), 256, 0, stream>>>(x1, x2, ln1_g, ln1_b, ln2_g, ln2_b, x1n, x2n);
    proj_kernel<<<dim3(M_ / 64, 4), 256, 0, stream>>>(x1n, x2n, wsw, bq, bv1, bk, bv2,
                                                      q1sw, k2sw, vsw8);
    flash2_kernel<<<dim3(M_ / 16), 512, 0, stream>>>(q1sw, k2sw, vsw8, att1, att2);
    attn_out_kernel<<<dim3(M_ / 32), 256, 0, stream>>>(att1, att2, wsw, bp1, bp2,
                                                       x1, x2, lnf_g, lnf_b, res, xn);
    ffn1_kernel<<<dim3(M_ / 64, 4), 256, 0, stream>>>(xn, wsw, bf1, h);
    ffn2_out_kernel<<<dim3(M_ / 32), 256, 0, stream>>>(h, wsw, bf2, res, ln3_g, ln3_b, bo, out);
}

// Round 14
// 235.250 us; speedup vs baseline: 1.3924x; 1.3924x over previous
//
#include <hip/hip_runtime.h>
#include <hip/hip_fp16.h>

typedef _Float16 half8 __attribute__((ext_vector_type(8)));
typedef float f32x4 __attribute__((ext_vector_type(4)));
typedef long lng2 __attribute__((ext_vector_type(2)));

#define B_   4
#define L_   4096
#define D_   128
#define M_   (B_*L_)     // 16384
#define D2_  256
#define H_   512
#define OUT_ 55

__device__ __forceinline__ f32x4 mfma16(half8 a, half8 b, f32x4 c) {
    return __builtin_amdgcn_mfma_f32_16x16x32_f16(a, b, c, 0, 0, 0);
}
__device__ __forceinline__ f32x4 mfma8(long a, long b, f32x4 c) {
    return __builtin_amdgcn_mfma_f32_16x16x32_fp8_fp8(a, b, c, 0, 0, 0);
}
// pack 4 floats -> 4 fp8 e4m3 bytes (OCP on gfx950)
__device__ __forceinline__ int pk4(float a, float b, float c, float d) {
    int t = __builtin_amdgcn_cvt_pk_fp8_f32(a, b, 0, false);
    return __builtin_amdgcn_cvt_pk_fp8_f32(c, d, t, true);
}
// raw v_exp_f32 — exp2f w/o fast-math lowers to OCML denorm-safe seq (~25cyc, r8 VALUBusy=47%)
__device__ __forceinline__ float fexp2(float x) { return __builtin_amdgcn_exp2f(x); }

// fold softmax scale (1/sqrt(128)) * log2(e) into k2 so score uses bare v_exp
#define KSCL (0.08838834764831845f * 1.4426950408889634f)

// ---- weight swizzle offsets (in halfs) within wsw region ----
#define WQ_OFF   0
#define WV1_OFF  16384
#define WK_OFF   32768
#define WV2_OFF  49152
#define WP1_OFF  65536
#define WP2_OFF  81920
#define WF1_OFF  98304     // 256x512 = 131072
#define WF2_OFF  229376    // 512x256 = 131072
#define WO_OFF   360448    // 256x64 (padded) = 16384

// Permuted k-map (within a 32-k chunk): k5 = (h<4 ? q*4+h : 16+q*4+(h-4)).
// Used for fp8 P & V and fp16 att & Wp1/Wp2 — A/B agree pairwise.
// NOTE (r13): score+pv fusion with LDS-resident P regressed 239->328 us —
// 16-row m-tiles re-read full q1+V per block (2 GB L2 traffic vs 128 MB P
// round-trip). P-through-memory two-pass is structurally better here.

// Pre-swizzle weights (fp32 row-major [K][N]) into B-fragment layout fp16.
// canonical: q=(k>>3)&3, j=k&7 ; permK (Wp1/Wp2 only): q=(k>>2)&3, j=(k&3)+4*((k>>4)&1)
// id==9: zero the rowsum buffer (absorbed zero_kernel — one less launch).
__global__ void prep_kernel(const float* Wq, const float* Wv1, const float* Wk,
                            const float* Wv2, const float* Wp1, const float* Wp2,
                            const float* Wf1, const float* Wf2, const float* Wo,
                            _Float16* wsw, float* rowsum) {
    int id = blockIdx.y;
    int t  = blockIdx.x * 256 + threadIdx.x;
    if (id == 9) {
        if (t < 4096) ((f32x4*)rowsum)[t] = f32x4{0.f, 0.f, 0.f, 0.f};
        return;
    }
    const float* src = nullptr; int K = 0, N = 0, Npad = 0, off = 0;
    switch (id) {
        case 0: src = Wq;  K = 128; N = 128; Npad = 128; off = WQ_OFF;  break;
        case 1: src = Wv1; K = 128; N = 128; Npad = 128; off = WV1_OFF; break;
        case 2: src = Wk;  K = 128; N = 128; Npad = 128; off = WK_OFF;  break;
        case 3: src = Wv2; K = 128; N = 128; Npad = 128; off = WV2_OFF; break;
        case 4: src = Wp1; K = 128; N = 128; Npad = 128; off = WP1_OFF; break;
        case 5: src = Wp2; K = 128; N = 128; Npad = 128; off = WP2_OFF; break;
        case 6: src = Wf1; K = 256; N = 512; Npad = 512; off = WF1_OFF; break;
        case 7: src = Wf2; K = 512; N = 256; Npad = 256; off = WF2_OFF; break;
        case 8: src = Wo;  K = 256; N = 55;  Npad = 64;  off = WO_OFF;  break;
        default: return;
    }
    int total = K * Npad;
    if (t >= total) return;
    int k = t / Npad, n = t % Npad;
    float v = (n < N) ? src[k * N + n] : 0.f;
    int s = k >> 5, c = n >> 4, ln = n & 15;
    int q, j;
    if (id == 4 || id == 5) { q = (k >> 2) & 3; j = (k & 3) + (((k >> 4) & 1) << 2); }
    else                    { q = (k >> 3) & 3; j = k & 7; }
    int nc = Npad >> 4;
    wsw[off + ((size_t)((s * nc + c) * 64 + q * 16 + ln)) * 8 + j] = (_Float16)v;
}

// FR layout for X[M][C] halfs:
// idx = ((lt*(C/32) + s)*64 + q*16 + ln_r)*8 + j ; lt=row>>4, ln_r=row&15,
// s=col>>5, q=(col>>3)&3, j=col&7.

// LayerNorm over D=128, one wave per token, fp32 in -> fp16 FR-swizzled out
__global__ __launch_bounds__(256) void ln_kernel(const float* x1, const float* x2,
        const float* g1, const float* b1, const float* g2, const float* b2,
        _Float16* x1n, _Float16* x2n) {
    int wave = threadIdx.x >> 6, lane = threadIdx.x & 63;
    int token = blockIdx.x * 4 + wave;
    const float* x = blockIdx.y ? x2 : x1;
    const float* g = blockIdx.y ? g2 : g1;
    const float* bb = blockIdx.y ? b2 : b1;
    _Float16* o = blockIdx.y ? x2n : x1n;
    const float* xr = x + (size_t)token * D_;
    float a0 = xr[lane], a1 = xr[lane + 64];
    float s = a0 + a1, s2 = a0 * a0 + a1 * a1;
    #pragma unroll
    for (int off = 1; off < 64; off <<= 1) {
        s += __shfl_xor(s, off);
        s2 += __shfl_xor(s2, off);
    }
    float mean = s * (1.f / 128.f);
    float var = s2 * (1.f / 128.f) - mean * mean;
    float inv = rsqrtf(var + 1e-5f);
    int lt = token >> 4, ln_r = token & 15;
    #pragma unroll
    for (int h = 0; h < 2; h++) {
        int col = lane + h * 64;
        float v = (h ? a1 : a0);
        float out = (v - mean) * inv * g[col] + bb[col];
        int ss = col >> 5, q = (col >> 3) & 3, j = col & 7;
        o[((size_t)((lt * 4 + ss) * 64 + q * 16 + ln_r)) * 8 + j] = (_Float16)out;
    }
}

// Projections. q1 fp16 FR; k2 fp16 FR pre-scaled by KSCL; v1/v2 -> vsw8 fp8
// permuted-k B-frag layout. W-frag register prefetch pipeline over c.
__global__ __launch_bounds__(256) void proj_kernel(const _Float16* x1n, const _Float16* x2n,
        const _Float16* wsw, const float* bq, const float* bv1, const float* bk,
        const float* bv2, _Float16* q1, _Float16* k2, unsigned char* vsw8) {
    int g = blockIdx.y;   // 0:Wq 1:Wv1 2:Wk 3:Wv2
    const _Float16* A = (g < 2) ? x1n : x2n;
    const _Float16* Bw = wsw + g * 16384;
    const float* bias = (g == 0) ? bq : (g == 1) ? bv1 : (g == 2) ? bk : bv2;
    int wave = threadIdx.x >> 6, lane = threadIdx.x & 63;
    int quad = lane >> 4, ln = lane & 15;
    int mbase = blockIdx.x * 64 + wave * 16;
    int lt = mbase >> 4;

    half8 a[4];
    #pragma unroll
    for (int s = 0; s < 4; s++)
        a[s] = *(const half8*)(A + ((size_t)((lt * 4 + s) * 64 + lane)) * 8);

    f32x4 acc[8];
    #pragma unroll
    for (int c = 0; c < 8; c++) acc[c] = f32x4{0.f, 0.f, 0.f, 0.f};

    half8 Wc[4], Wn[4];
    #pragma unroll
    for (int s = 0; s < 4; s++)
        Wc[s] = *(const half8*)(Bw + ((size_t)((s * 8 + 0) * 64 + lane)) * 8);
    #pragma unroll
    for (int c = 0; c < 8; c++) {
        int cn = (c < 7) ? c + 1 : 7;
        #pragma unroll
        for (int s = 0; s < 4; s++)
            Wn[s] = *(const half8*)(Bw + ((size_t)((s * 8 + cn) * 64 + lane)) * 8);
        #pragma unroll
        for (int s = 0; s < 4; s++)
            acc[c] = mfma16(a[s], Wc[s], acc[c]);
        #pragma unroll
        for (int s = 0; s < 4; s++) Wc[s] = Wn[s];
    }

    bool isV = (g == 1) || (g == 3);
    if (!isV) {
        float scl = (g == 2) ? KSCL : 1.f;
        _Float16* out = (g == 0) ? q1 : k2;
        #pragma unroll
        for (int c = 0; c < 8; c++) {
            int n = c * 16 + ln;
            float bv = bias[n];
            #pragma unroll
            for (int r = 0; r < 4; r++) {
                int s_o = c >> 1, q_o = ((c & 1) << 1) | (ln >> 3), j = ln & 7;
                out[((size_t)((lt * 4 + s_o) * 64 + q_o * 16 + (quad * 4 + r))) * 8 + j]
                    = (_Float16)((acc[c][r] + bv) * scl);
            }
        }
    } else {
        int cbase = (g == 3) ? 8 : 0;
        int b = mbase >> 12;
        int l0 = (mbase & (L_ - 1)) + quad * 4;
        int sp = l0 >> 6, tt = (l0 >> 4) & 3, q2 = (l0 >> 2) & 3;
        unsigned char* Vb = vsw8 + (size_t)b * (1u << 20);
        #pragma unroll
        for (int c = 0; c < 8; c++) {
            int n = c * 16 + ln;
            float bv = bias[n];
            int pk = pk4(acc[c][0] + bv, acc[c][1] + bv, acc[c][2] + bv, acc[c][3] + bv);
            *(int*)(Vb + (((size_t)(sp * 16 + cbase + c) * 64 + q2 * 16 + ln) * 16 + tt * 4)) = pk;
        }
    }
}

// Pass 1: S^T tiles (A=q1 rows = softmax k-dim, B=k2^T cols = att rows).
// p = exp2(acc) via raw v_exp_f32; pk4 over r -> permuted-k fp8 A-entries.
__global__ __launch_bounds__(256) void score_kernel(
        const _Float16* __restrict__ q1sw, const _Float16* __restrict__ k2sw,
        unsigned char* __restrict__ pmat8, float* __restrict__ rowsum) {
    int w = threadIdx.x >> 6, lane = threadIdx.x & 63;
    int quad = lane >> 4, ln = lane & 15;
    int b = blockIdx.z;
    int kL0 = blockIdx.y * 128 + (w & 1) * 64;     // q1 rows (contraction dim of PV)
    int mL0 = blockIdx.x * 128 + (w >> 1) * 64;    // k2 rows (att rows)
    int ltk = ((b << 12) + kL0) >> 4;
    int ltm = ((b << 12) + mL0) >> 4;

    f32x4 acc[4][4];
    #pragma unroll
    for (int i = 0; i < 4; i++)
        #pragma unroll
        for (int j = 0; j < 4; j++) acc[i][j] = f32x4{0.f, 0.f, 0.f, 0.f};

    #pragma unroll
    for (int s = 0; s < 4; s++) {
        half8 a[4], bq[4];
        #pragma unroll
        for (int i = 0; i < 4; i++)
            a[i] = *(const half8*)(q1sw + ((size_t)(((ltk + i) * 4 + s) * 64 + lane)) * 8);
        #pragma unroll
        for (int j = 0; j < 4; j++)
            bq[j] = *(const half8*)(k2sw + ((size_t)(((ltm + j) * 4 + s) * 64 + lane)) * 8);
        #pragma unroll
        for (int i = 0; i < 4; i++)
            #pragma unroll
            for (int j = 0; j < 4; j++)
                acc[i][j] = mfma16(a[i], bq[j], acc[i][j]);
    }

    unsigned char* Pb = pmat8 + (size_t)b * (16u << 20);
    int sp = kL0 >> 6;
    #pragma unroll
    for (int j = 0; j < 4; j++) {
        int4 d;
        float csum = 0.f;
        #pragma unroll
        for (int i = 0; i < 4; i++) {
            float p0 = fexp2(acc[i][j][0]);
            float p1 = fexp2(acc[i][j][1]);
            float p2 = fexp2(acc[i][j][2]);
            float p3 = fexp2(acc[i][j][3]);
            csum += (p0 + p1) + (p2 + p3);
            ((int*)&d)[i] = pk4(p0, p1, p2, p3);
        }
        csum += __shfl_xor(csum, 16);
        csum += __shfl_xor(csum, 32);
        if (lane < 16)
            atomicAdd(&rowsum[(b << 12) + mL0 + j * 16 + ln], csum);
        int lt = (mL0 >> 4) + j;
        *(int4*)(Pb + (((size_t)(lt * 64 + sp)) * 64 + lane) * 16) = d;
    }
}

// Pass 2: O^T = V^T . P^T (operand swap). 512-thread blocks, 8 waves:
// wave (wc, kh) = (n-quarter, k-half). In-block k-split -> 4 waves/SIMD.
// fp32 partials merged in LDS. att-row lands on lane axis.
__global__ __launch_bounds__(512) void pv_kernel(
        const unsigned char* __restrict__ pmat8, const unsigned char* __restrict__ vsw8,
        const float* __restrict__ rowsum,
        _Float16* __restrict__ att1, _Float16* __restrict__ att2) {
    __shared__ f32x4 part[4][2][4][64];   // 32 KB: [wc][m c][n i][lane]
    int w = threadIdx.x >> 6, lane = threadIdx.x & 63;
    int quad = lane >> 4, ln = lane & 15;
    int wc = w & 3, kh = w >> 2;
    int rowG0 = blockIdx.x * 32;
    int b = rowG0 >> 12;
    int lt0 = (rowG0 & (L_ - 1)) >> 4;   // 2 m-tiles
    const unsigned char* Pb = pmat8 + (size_t)b * (16u << 20);
    const unsigned char* Vb = vsw8 + (size_t)b * (1u << 20);
    int c0 = wc * 4;
    int sp0 = kh * 32;

    f32x4 acc[4][2];
    #pragma unroll
    for (int i = 0; i < 4; i++)
        #pragma unroll
        for (int c = 0; c < 2; c++) acc[i][c] = f32x4{0.f, 0.f, 0.f, 0.f};

    lng2 Vf[2][4], Pf[2][2];
    #pragma unroll
    for (int p = 0; p < 2; p++) {
        #pragma unroll
        for (int i = 0; i < 4; i++)
            Vf[p][i] = *(const lng2*)(Vb + (((size_t)((sp0 + p) * 16 + c0 + i)) * 64 + lane) * 16);
        #pragma unroll
        for (int c = 0; c < 2; c++)
            Pf[p][c] = *(const lng2*)(Pb + (((size_t)((lt0 + c) * 64 + sp0 + p)) * 64 + lane) * 16);
    }

    #define PVSTEP(buf, ii) do {                                                     \
        int spn = sp0 + ((((ii) + 2) < 32) ? (ii) + 2 : 31);                         \
        lng2 Vn[4], Pn[2];                                                           \
        _Pragma("unroll")                                                            \
        for (int i = 0; i < 4; i++)                                                  \
            Vn[i] = *(const lng2*)(Vb + (((size_t)(spn * 16 + c0 + i)) * 64 + lane) * 16); \
        _Pragma("unroll")                                                            \
        for (int c = 0; c < 2; c++)                                                  \
            Pn[c] = *(const lng2*)(Pb + (((size_t)((lt0 + c) * 64 + spn)) * 64 + lane) * 16); \
        _Pragma("unroll")                                                            \
        for (int i = 0; i < 4; i++)                                                  \
            _Pragma("unroll")                                                        \
            for (int c = 0; c < 2; c++) {                                            \
                acc[i][c] = mfma8(Vf[buf][i].x, Pf[buf][c].x, acc[i][c]);             \
                acc[i][c] = mfma8(Vf[buf][i].y, Pf[buf][c].y, acc[i][c]);             \
            }                                                                        \
        _Pragma("unroll")                                                            \
        for (int i = 0; i < 4; i++) Vf[buf][i] = Vn[i];                              \
        _Pragma("unroll")                                                            \
        for (int c = 0; c < 2; c++) Pf[buf][c] = Pn[c];                              \
    } while (0)

    for (int ii = 0; ii < 32; ii += 2) {
        PVSTEP(0, ii);
        PVSTEP(1, ii + 1);
    }
    #undef PVSTEP

    if (kh == 1) {
        #pragma unroll
        for (int i = 0; i < 4; i++)
            #pragma unroll
            for (int c = 0; c < 2; c++)
                part[wc][c][i][lane] = acc[i][c];
    }
    __syncthreads();
    if (kh == 0) {
        #pragma unroll
        for (int i = 0; i < 4; i++)
            #pragma unroll
            for (int c = 0; c < 2; c++)
                acc[i][c] += part[wc][c][i][lane];

        _Float16* att = (wc >= 2) ? att2 : att1;
        #pragma unroll
        for (int c = 0; c < 2; c++) {
            float inv = 1.f / rowsum[rowG0 + c * 16 + ln];
            int lt = (rowG0 >> 4) + c;
            #pragma unroll
            for (int sl = 0; sl < 2; sl++) {
                half8 v;
                #pragma unroll
                for (int r = 0; r < 4; r++) {
                    v[r]     = (_Float16)(acc[2 * sl][c][r] * inv);
                    v[r + 4] = (_Float16)(acc[2 * sl + 1][c][r] * inv);
                }
                int s = (wc & 1) * 2 + sl;
                *(half8*)(att + ((size_t)((lt * 4 + s) * 64 + lane)) * 8) = v;
            }
        }
    }
}

// out_s = att_s @ Wp_s + bias + residual ; concat -> res (fp16) ; LNf -> xn (FR fp16)
// 512 blocks x (2 rowtiles x 2 streams).
__global__ __launch_bounds__(256) void attn_out_kernel(const _Float16* att1, const _Float16* att2,
        const _Float16* wsw, const float* bp1, const float* bp2,
        const float* x1, const float* x2, const float* lnf_g, const float* lnf_b,
        _Float16* res, _Float16* xn) {
    __shared__ float sst[2][16][2][2];
    int w = threadIdx.x >> 6, lane = threadIdx.x & 63;
    int quad = lane >> 4, ln = lane & 15;
    int rt = w & 1, st = w >> 1;
    int mbase = blockIdx.x * 32 + rt * 16;
    int lt = mbase >> 4;
    const _Float16* att = st ? att2 : att1;
    const _Float16* Wp = wsw + (st ? WP2_OFF : WP1_OFF);
    const float* bp = st ? bp2 : bp1;
    const float* xres = st ? x2 : x1;

    half8 a[4];
    #pragma unroll
    for (int s = 0; s < 4; s++)
        a[s] = *(const half8*)(att + ((size_t)((lt * 4 + s) * 64 + lane)) * 8);

    f32x4 y[8];
    #pragma unroll
    for (int c = 0; c < 8; c++) y[c] = f32x4{0,0,0,0};

    half8 Wc[4], Wn[4];
    #pragma unroll
    for (int s = 0; s < 4; s++)
        Wc[s] = *(const half8*)(Wp + ((size_t)((s * 8 + 0) * 64 + lane)) * 8);
    #pragma unroll
    for (int c = 0; c < 8; c++) {
        int cn = (c < 7) ? c + 1 : 7;
        #pragma unroll
        for (int s = 0; s < 4; s++)
            Wn[s] = *(const half8*)(Wp + ((size_t)((s * 8 + cn) * 64 + lane)) * 8);
        #pragma unroll
        for (int s = 0; s < 4; s++)
            y[c] = mfma16(a[s], Wc[s], y[c]);
        #pragma unroll
        for (int s = 0; s < 4; s++) Wc[s] = Wn[s];
    }

    float psum[4] = {0,0,0,0}, psq[4] = {0,0,0,0};
    #pragma unroll
    for (int c = 0; c < 8; c++) {
        int n = c * 16 + ln;
        float bv = bp[n];
        #pragma unroll
        for (int r = 0; r < 4; r++) {
            int m = mbase + quad * 4 + r;
            float v = y[c][r] + bv + xres[(size_t)m * D_ + n];
            y[c][r] = v; psum[r] += v; psq[r] += v * v;
        }
    }
    #pragma unroll
    for (int off = 1; off < 16; off <<= 1)
        #pragma unroll
        for (int r = 0; r < 4; r++) { psum[r] += __shfl_xor(psum[r], off); psq[r] += __shfl_xor(psq[r], off); }
    if (ln == 0)
        #pragma unroll
        for (int r = 0; r < 4; r++) {
            sst[rt][quad * 4 + r][st][0] = psum[r];
            sst[rt][quad * 4 + r][st][1] = psq[r];
        }
    __syncthreads();
    #pragma unroll
    for (int r = 0; r < 4; r++) {
        float su = sst[rt][quad * 4 + r][0][0] + sst[rt][quad * 4 + r][1][0];
        float sq = sst[rt][quad * 4 + r][0][1] + sst[rt][quad * 4 + r][1][1];
        float mean = su * (1.f / 256.f);
        float var = sq * (1.f / 256.f) - mean * mean;
        float inv = rsqrtf(var + 1e-5f);
        int m = mbase + quad * 4 + r;
        int lt_m = m >> 4;
        #pragma unroll
        for (int c = 0; c < 8; c++) {
            int colg = st * 128 + c * 16 + ln;
            res[(size_t)m * D2_ + colg] = (_Float16)y[c][r];
            float yn = (y[c][r] - mean) * inv * lnf_g[colg] + lnf_b[colg];
            int s_x = colg >> 5, q_x = (colg >> 3) & 3, j = colg & 7;
            xn[((size_t)((lt_m * 8 + s_x) * 64 + q_x * 16 + (m & 15))) * 8 + j] = (_Float16)yn;
        }
    }
}

// h = gelu(xn @ Wf1 + bf1)  [M x 512], FR in/out. W-prefetch pipeline; fast
// tanh-form GELU (x*sigmoid(2u)) via raw v_exp.
__global__ __launch_bounds__(256) void ffn1_kernel(const _Float16* xn, const _Float16* wsw,
        const float* bf1, _Float16* h) {
    int wave = threadIdx.x >> 6, lane = threadIdx.x & 63;
    int quad = lane >> 4, ln = lane & 15;
    int mbase = blockIdx.x * 64 + wave * 16;
    int lt = mbase >> 4;
    int nt = blockIdx.y;   // 0..3
    const _Float16* W = wsw + WF1_OFF;   // K=256, N=512, nc=32

    half8 a[8];
    #pragma unroll
    for (int s = 0; s < 8; s++)
        a[s] = *(const half8*)(xn + ((size_t)((lt * 8 + s) * 64 + lane)) * 8);

    f32x4 acc[8];
    #pragma unroll
    for (int c = 0; c < 8; c++) acc[c] = f32x4{0,0,0,0};

    half8 Wc[8], Wn[8];
    #pragma unroll
    for (int s = 0; s < 8; s++)
        Wc[s] = *(const half8*)(W + ((size_t)((s * 32 + nt * 8) * 64 + lane)) * 8);
    #pragma unroll
    for (int c = 0; c < 8; c++) {
        int cn = (c < 7) ? c + 1 : 7;
        #pragma unroll
        for (int s = 0; s < 8; s++)
            Wn[s] = *(const half8*)(W + ((size_t)((s * 32 + nt * 8 + cn) * 64 + lane)) * 8);
        #pragma unroll
        for (int s = 0; s < 8; s++)
            acc[c] = mfma16(a[s], Wc[s], acc[c]);
        #pragma unroll
        for (int s = 0; s < 8; s++) Wc[s] = Wn[s];
    }
    #pragma unroll
    for (int c = 0; c < 8; c++) {
        int n = nt * 128 + c * 16 + ln;
        float bv = bf1[n];
        int s_h = n >> 5, q_h = (n >> 3) & 3, j = n & 7;
        #pragma unroll
        for (int r = 0; r < 4; r++) {
            float v = acc[c][r] + bv;
            float u = 0.7978845608f * (v + 0.044715f * v * v * v);
            float e = fexp2(-2.8853900818f * u);     // 2*log2(e)*u
            float ge = v * __builtin_amdgcn_rcpf(1.f + e);
            h[((size_t)((lt * 16 + s_h) * 64 + q_h * 16 + (quad * 4 + r))) * 8 + j] = (_Float16)ge;
        }
    }
}

// FUSED: xn2 = LN3(h @ Wf2 + bf2 + res) -> LDS tile ; out = xn2 @ Wo + bo.
__global__ __launch_bounds__(256) void ffn2_out_kernel(const _Float16* h, const _Float16* wsw,
        const float* bf2, const _Float16* res, const float* g3, const float* b3,
        const float* bo, float* out) {
    __shared__ float sst[2][16][2][2];
    __shared__ _Float16 xt[8192];        // 16 KB: 32 rows x 256 cols, FR layout
    __shared__ f32x4 pc[2][4][64];       // 8 KB: out k-half partials
    int w = threadIdx.x >> 6, lane = threadIdx.x & 63;
    int quad = lane >> 4, ln = lane & 15;
    int rt = w & 1, nh = w >> 1;
    int mb = blockIdx.x * 32 + rt * 16;
    int lt = mb >> 4;
    const _Float16* W = wsw + WF2_OFF;   // K=512, N=256, nc=16

    f32x4 acc[8];
    #pragma unroll
    for (int c = 0; c < 8; c++) acc[c] = f32x4{0,0,0,0};

    half8 aC, aN;
    half8 Wc[8], Wn[8];
    aC = *(const half8*)(h + ((size_t)((lt * 16 + 0) * 64 + lane)) * 8);
    #pragma unroll
    for (int c = 0; c < 8; c++)
        Wc[c] = *(const half8*)(W + ((size_t)((0 * 16 + nh * 8 + c) * 64 + lane)) * 8);

    #pragma unroll
    for (int s = 0; s < 16; s++) {
        int sn = (s < 15) ? s + 1 : 15;
        aN = *(const half8*)(h + ((size_t)((lt * 16 + sn) * 64 + lane)) * 8);
        #pragma unroll
        for (int c = 0; c < 8; c++)
            Wn[c] = *(const half8*)(W + ((size_t)((sn * 16 + nh * 8 + c) * 64 + lane)) * 8);
        #pragma unroll
        for (int c = 0; c < 8; c++)
            acc[c] = mfma16(aC, Wc[c], acc[c]);
        aC = aN;
        #pragma unroll
        for (int c = 0; c < 8; c++) Wc[c] = Wn[c];
    }

    float y[8][4];
    float psum[4] = {0,0,0,0}, psq[4] = {0,0,0,0};
    #pragma unroll
    for (int c = 0; c < 8; c++) {
        int n = nh * 128 + c * 16 + ln;
        float bv = bf2[n];
        #pragma unroll
        for (int r = 0; r < 4; r++) {
            int m = mb + quad * 4 + r;
            float v = acc[c][r] + bv + (float)res[(size_t)m * D2_ + n];
            y[c][r] = v; psum[r] += v; psq[r] += v * v;
        }
    }
    #pragma unroll
    for (int off = 1; off < 16; off <<= 1)
        #pragma unroll
        for (int r = 0; r < 4; r++) { psum[r] += __shfl_xor(psum[r], off); psq[r] += __shfl_xor(psq[r], off); }
    if (ln == 0)
        #pragma unroll
        for (int r = 0; r < 4; r++) { sst[rt][quad * 4 + r][nh][0] = psum[r]; sst[rt][quad * 4 + r][nh][1] = psq[r]; }
    __syncthreads();
    #pragma unroll
    for (int r = 0; r < 4; r++) {
        float su = sst[rt][quad * 4 + r][0][0] + sst[rt][quad * 4 + r][1][0];
        float sq = sst[rt][quad * 4 + r][0][1] + sst[rt][quad * 4 + r][1][1];
        float mean = su * (1.f / 256.f);
        float var = sq * (1.f / 256.f) - mean * mean;
        float invs = rsqrtf(var + 1e-5f);
        #pragma unroll
        for (int c = 0; c < 8; c++) {
            int n = nh * 128 + c * 16 + ln;
            float yn = (y[c][r] - mean) * invs * g3[n] + b3[n];
            int s_x = n >> 5, q_x = (n >> 3) & 3, j = n & 7;
            xt[((rt * 8 + s_x) * 64 + q_x * 16 + (quad * 4 + r)) * 8 + j] = (_Float16)yn;
        }
    }
    __syncthreads();

    // ---- out phase: waves (rt2, kh) ----
    int rt2 = w & 1, kh = w >> 1;
    const _Float16* Wo = wsw + WO_OFF;   // K=256, N=64(padded), nc=4
    f32x4 oacc[4];
    #pragma unroll
    for (int c = 0; c < 4; c++) oacc[c] = f32x4{0,0,0,0};
    #pragma unroll
    for (int ss = 0; ss < 4; ss++) {
        int s = kh * 4 + ss;
        half8 a = *(const half8*)(xt + ((size_t)((rt2 * 8 + s) * 64 + lane)) * 8);
        #pragma unroll
        for (int c = 0; c < 4; c++)
            oacc[c] = mfma16(a, *(const half8*)(Wo + ((size_t)((s * 4 + c) * 64 + lane)) * 8), oacc[c]);
    }
    if (kh == 1)
        #pragma unroll
        for (int c = 0; c < 4; c++) pc[rt2][c][lane] = oacc[c];
    __syncthreads();
    if (kh == 0) {
        int mb2 = blockIdx.x * 32 + rt2 * 16;
        #pragma unroll
        for (int c = 0; c < 4; c++) {
            f32x4 p = pc[rt2][c][lane];
            int n = c * 16 + ln;
            if (n < OUT_) {
                float bv = bo[n];
                #pragma unroll
                for (int r = 0; r < 4; r++)
                    out[(size_t)(mb2 + quad * 4 + r) * OUT_ + n] = oacc[c][r] + p[r] + bv;
            }
        }
    }
}

extern "C" void kernel_launch(void* const* d_in, const int* in_sizes, int n_in,
                              void* d_out, int out_size, void* d_ws, size_t ws_size,
                              hipStream_t stream) {
    const float* x1    = (const float*)d_in[0];
    const float* x2    = (const float*)d_in[1];
    const float* ln1_g = (const float*)d_in[2];
    const float* ln1_b = (const float*)d_in[3];
    const float* ln2_g = (const float*)d_in[4];
    const float* ln2_b = (const float*)d_in[5];
    const float* Wq    = (const float*)d_in[6];
    const float* bq    = (const float*)d_in[7];
    const float* Wv1   = (const float*)d_in[8];
    const float* bv1   = (const float*)d_in[9];
    const float* Wk    = (const float*)d_in[10];
    const float* bk    = (const float*)d_in[11];
    const float* Wv2   = (const float*)d_in[12];
    const float* bv2   = (const float*)d_in[13];
    const float* Wp1   = (const float*)d_in[14];
    const float* bp1   = (const float*)d_in[15];
    const float* Wp2   = (const float*)d_in[16];
    const float* bp2   = (const float*)d_in[17];
    const float* lnf_g = (const float*)d_in[18];
    const float* lnf_b = (const float*)d_in[19];
    const float* Wf1   = (const float*)d_in[20];
    const float* bf1   = (const float*)d_in[21];
    const float* Wf2   = (const float*)d_in[22];
    const float* bf2   = (const float*)d_in[23];
    const float* ln3_g = (const float*)d_in[24];
    const float* ln3_b = (const float*)d_in[25];
    const float* Wo    = (const float*)d_in[26];
    const float* bo    = (const float*)d_in[27];
    float* out = (float*)d_out;

    char* ws = (char*)d_ws;
    const size_t MB = 1 << 20;
    _Float16* q1sw   = (_Float16*)(ws + 0 * MB);    // 4 MB
    _Float16* k2sw   = (_Float16*)(ws + 4 * MB);    // 4 MB
    unsigned char* vsw8 = (unsigned char*)(ws + 8 * MB);   // 4 MB (fp8 Vcat per batch)
    _Float16* att1   = (_Float16*)(ws + 12 * MB);   // 4 MB
    _Float16* att2   = (_Float16*)(ws + 16 * MB);   // 4 MB
    _Float16* x1n    = (_Float16*)(ws + 20 * MB);   // 4 MB
    _Float16* x2n    = (_Float16*)(ws + 24 * MB);   // 4 MB
    _Float16* wsw    = (_Float16*)(ws + 28 * MB);   // ~0.74 MB
    float*    rowsum = (float*)   (ws + 29 * MB);   // 64 KB
    _Float16* res    = (_Float16*)(ws + 30 * MB);   // 8 MB
    _Float16* xn     = (_Float16*)(ws + 46 * MB);   // 8 MB
    _Float16* h      = (_Float16*)(ws + 54 * MB);   // 16 MB
    unsigned char* pmat8 = (unsigned char*)(ws + 78 * MB); // 64 MB (fp8 P per batch)

    prep_kernel<<<dim3(512, 10), 256, 0, stream>>>(Wq, Wv1, Wk, Wv2, Wp1, Wp2, Wf1, Wf2, Wo,
                                                   wsw, rowsum);
    ln_kernel<<<dim3(M_ / 4, 2), 256, 0, stream>>>(x1, x2, ln1_g, ln1_b, ln2_g, ln2_b, x1n, x2n);
    proj_kernel<<<dim3(M_ / 64, 4), 256, 0, stream>>>(x1n, x2n, wsw, bq, bv1, bk, bv2,
                                                      q1sw, k2sw, vsw8);
    score_kernel<<<dim3(32, 32, 4), 256, 0, stream>>>(q1sw, k2sw, pmat8, rowsum);
    pv_kernel<<<dim3(M_ / 32), 512, 0, stream>>>(pmat8, vsw8, rowsum, att1, att2);
    attn_out_kernel<<<dim3(M_ / 32), 256, 0, stream>>>(att1, att2, wsw, bp1, bp2,
                                                       x1, x2, lnf_g, lnf_b, res, xn);
    ffn1_kernel<<<dim3(M_ / 64, 4), 256, 0, stream>>>(xn, wsw, bf1, h);
    ffn2_out_kernel<<<dim3(M_ / 32), 256, 0, stream>>>(h, wsw, bf2, res, ln3_g, ln3_b, bo, out);
}

// Round 15
// 233.078 us; speedup vs baseline: 1.4054x; 1.0093x over previous
//
#include <hip/hip_runtime.h>
#include <hip/hip_fp16.h>

typedef _Float16 half8 __attribute__((ext_vector_type(8)));
typedef float f32x4 __attribute__((ext_vector_type(4)));
typedef long lng2 __attribute__((ext_vector_type(2)));

#define B_   4
#define L_   4096
#define D_   128
#define M_   (B_*L_)     // 16384
#define D2_  256
#define H_   512
#define OUT_ 55

__device__ __forceinline__ f32x4 mfma16(half8 a, half8 b, f32x4 c) {
    return __builtin_amdgcn_mfma_f32_16x16x32_f16(a, b, c, 0, 0, 0);
}
__device__ __forceinline__ f32x4 mfma8(long a, long b, f32x4 c) {
    return __builtin_amdgcn_mfma_f32_16x16x32_fp8_fp8(a, b, c, 0, 0, 0);
}
// pack 4 floats -> 4 fp8 e4m3 bytes (OCP on gfx950)
__device__ __forceinline__ int pk4(float a, float b, float c, float d) {
    int t = __builtin_amdgcn_cvt_pk_fp8_f32(a, b, 0, false);
    return __builtin_amdgcn_cvt_pk_fp8_f32(c, d, t, true);
}
// raw v_exp_f32 — exp2f w/o fast-math lowers to OCML denorm-safe seq (~25cyc, r8 VALUBusy=47%)
__device__ __forceinline__ float fexp2(float x) { return __builtin_amdgcn_exp2f(x); }

// fold softmax scale (1/sqrt(128)) * log2(e) into k2 so score uses bare v_exp
#define KSCL (0.08838834764831845f * 1.4426950408889634f)

// ---- weight swizzle offsets (in halfs) within wsw region ----
#define WQ_OFF   0
#define WV1_OFF  16384
#define WK_OFF   32768
#define WV2_OFF  49152
#define WP1_OFF  65536
#define WP2_OFF  81920
#define WF1_OFF  98304     // 256x512 = 131072
#define WF2_OFF  229376    // 512x256 = 131072
#define WO_OFF   360448    // 256x64 (padded) = 16384

// Permuted k-map (within a 32-k chunk): k5 = (h<4 ? q*4+h : 16+q*4+(h-4)).
// Used for fp8 P & V and fp16 att & Wp1/Wp2 — A/B agree pairwise.
// NOTE (r13): score+pv fusion with LDS-resident P regressed 239->328 us —
// 16-row m-tiles re-read full q1+V per block (2 GB L2 traffic vs 128 MB P
// round-trip). P-through-memory two-pass is structurally better here.

// Pre-swizzle weights (fp32 row-major [K][N]) into B-fragment layout fp16.
// canonical: q=(k>>3)&3, j=k&7 ; permK (Wp1/Wp2 only): q=(k>>2)&3, j=(k&3)+4*((k>>4)&1)
// id==9: zero the rowsum buffer (absorbed zero_kernel — one less launch).
__global__ void prep_kernel(const float* Wq, const float* Wv1, const float* Wk,
                            const float* Wv2, const float* Wp1, const float* Wp2,
                            const float* Wf1, const float* Wf2, const float* Wo,
                            _Float16* wsw, float* rowsum) {
    int id = blockIdx.y;
    int t  = blockIdx.x * 256 + threadIdx.x;
    if (id == 9) {
        if (t < 4096) ((f32x4*)rowsum)[t] = f32x4{0.f, 0.f, 0.f, 0.f};
        return;
    }
    const float* src = nullptr; int K = 0, N = 0, Npad = 0, off = 0;
    switch (id) {
        case 0: src = Wq;  K = 128; N = 128; Npad = 128; off = WQ_OFF;  break;
        case 1: src = Wv1; K = 128; N = 128; Npad = 128; off = WV1_OFF; break;
        case 2: src = Wk;  K = 128; N = 128; Npad = 128; off = WK_OFF;  break;
        case 3: src = Wv2; K = 128; N = 128; Npad = 128; off = WV2_OFF; break;
        case 4: src = Wp1; K = 128; N = 128; Npad = 128; off = WP1_OFF; break;
        case 5: src = Wp2; K = 128; N = 128; Npad = 128; off = WP2_OFF; break;
        case 6: src = Wf1; K = 256; N = 512; Npad = 512; off = WF1_OFF; break;
        case 7: src = Wf2; K = 512; N = 256; Npad = 256; off = WF2_OFF; break;
        case 8: src = Wo;  K = 256; N = 55;  Npad = 64;  off = WO_OFF;  break;
        default: return;
    }
    int total = K * Npad;
    if (t >= total) return;
    int k = t / Npad, n = t % Npad;
    float v = (n < N) ? src[k * N + n] : 0.f;
    int s = k >> 5, c = n >> 4, ln = n & 15;
    int q, j;
    if (id == 4 || id == 5) { q = (k >> 2) & 3; j = (k & 3) + (((k >> 4) & 1) << 2); }
    else                    { q = (k >> 3) & 3; j = k & 7; }
    int nc = Npad >> 4;
    wsw[off + ((size_t)((s * nc + c) * 64 + q * 16 + ln)) * 8 + j] = (_Float16)v;
}

// FR layout for X[M][C] halfs:
// idx = ((lt*(C/32) + s)*64 + q*16 + ln_r)*8 + j ; lt=row>>4, ln_r=row&15,
// s=col>>5, q=(col>>3)&3, j=col&7.

// Projections with FUSED input LayerNorm (r15: ln_kernel absorbed — A-frag
// row lives on lane ln, its 128 cols spread over the 4 quads, so per-row LN
// is 2 shfl_xor reductions). q1 fp16 FR; k2 fp16 FR pre-scaled by KSCL;
// v1/v2 -> vsw8 fp8 permuted-k B-frag layout. W-frag prefetch pipeline.
__global__ __launch_bounds__(256) void proj_kernel(const float* x1, const float* x2,
        const _Float16* wsw,
        const float* ln1_g, const float* ln1_b, const float* ln2_g, const float* ln2_b,
        const float* bq, const float* bv1, const float* bk, const float* bv2,
        _Float16* q1, _Float16* k2, unsigned char* vsw8) {
    int g = blockIdx.y;   // 0:Wq 1:Wv1 2:Wk 3:Wv2
    const float* X  = (g < 2) ? x1 : x2;
    const float* lg = (g < 2) ? ln1_g : ln2_g;
    const float* lb = (g < 2) ? ln1_b : ln2_b;
    const _Float16* Bw = wsw + g * 16384;
    const float* bias = (g == 0) ? bq : (g == 1) ? bv1 : (g == 2) ? bk : bv2;
    int wave = threadIdx.x >> 6, lane = threadIdx.x & 63;
    int quad = lane >> 4, ln = lane & 15;
    int mbase = blockIdx.x * 64 + wave * 16;
    int lt = mbase >> 4;

    // ---- fused LN: this lane holds row (mbase+ln), cols s*32+quad*8..+7 ----
    const float* xr = X + (size_t)(mbase + ln) * D_;
    float xv[4][8];
    float sum = 0.f, sq = 0.f;
    #pragma unroll
    for (int s = 0; s < 4; s++) {
        f32x4 v0 = *(const f32x4*)(xr + s * 32 + quad * 8);
        f32x4 v1 = *(const f32x4*)(xr + s * 32 + quad * 8 + 4);
        #pragma unroll
        for (int j = 0; j < 4; j++) {
            xv[s][j]     = v0[j];
            xv[s][j + 4] = v1[j];
            sum += v0[j] + v1[j];
            sq  += v0[j] * v0[j] + v1[j] * v1[j];
        }
    }
    // rows are striped across lanes {ln, ln+16, ln+32, ln+48}
    sum += __shfl_xor(sum, 16); sum += __shfl_xor(sum, 32);
    sq  += __shfl_xor(sq, 16);  sq  += __shfl_xor(sq, 32);
    float mean = sum * (1.f / 128.f);
    float var  = sq * (1.f / 128.f) - mean * mean;
    float inv  = rsqrtf(var + 1e-5f);
    half8 a[4];
    #pragma unroll
    for (int s = 0; s < 4; s++) {
        f32x4 g0 = *(const f32x4*)(lg + s * 32 + quad * 8);
        f32x4 g1 = *(const f32x4*)(lg + s * 32 + quad * 8 + 4);
        f32x4 b0 = *(const f32x4*)(lb + s * 32 + quad * 8);
        f32x4 b1 = *(const f32x4*)(lb + s * 32 + quad * 8 + 4);
        #pragma unroll
        for (int j = 0; j < 4; j++) {
            a[s][j]     = (_Float16)((xv[s][j] - mean) * inv * g0[j] + b0[j]);
            a[s][j + 4] = (_Float16)((xv[s][j + 4] - mean) * inv * g1[j] + b1[j]);
        }
    }

    f32x4 acc[8];
    #pragma unroll
    for (int c = 0; c < 8; c++) acc[c] = f32x4{0.f, 0.f, 0.f, 0.f};

    half8 Wc[4], Wn[4];
    #pragma unroll
    for (int s = 0; s < 4; s++)
        Wc[s] = *(const half8*)(Bw + ((size_t)((s * 8 + 0) * 64 + lane)) * 8);
    #pragma unroll
    for (int c = 0; c < 8; c++) {
        int cn = (c < 7) ? c + 1 : 7;
        #pragma unroll
        for (int s = 0; s < 4; s++)
            Wn[s] = *(const half8*)(Bw + ((size_t)((s * 8 + cn) * 64 + lane)) * 8);
        #pragma unroll
        for (int s = 0; s < 4; s++)
            acc[c] = mfma16(a[s], Wc[s], acc[c]);
        #pragma unroll
        for (int s = 0; s < 4; s++) Wc[s] = Wn[s];
    }

    bool isV = (g == 1) || (g == 3);
    if (!isV) {
        float scl = (g == 2) ? KSCL : 1.f;
        _Float16* out = (g == 0) ? q1 : k2;
        #pragma unroll
        for (int c = 0; c < 8; c++) {
            int n = c * 16 + ln;
            float bv = bias[n];
            #pragma unroll
            for (int r = 0; r < 4; r++) {
                int s_o = c >> 1, q_o = ((c & 1) << 1) | (ln >> 3), j = ln & 7;
                out[((size_t)((lt * 4 + s_o) * 64 + q_o * 16 + (quad * 4 + r))) * 8 + j]
                    = (_Float16)((acc[c][r] + bv) * scl);
            }
        }
    } else {
        int cbase = (g == 3) ? 8 : 0;
        int b = mbase >> 12;
        int l0 = (mbase & (L_ - 1)) + quad * 4;
        int sp = l0 >> 6, tt = (l0 >> 4) & 3, q2 = (l0 >> 2) & 3;
        unsigned char* Vb = vsw8 + (size_t)b * (1u << 20);
        #pragma unroll
        for (int c = 0; c < 8; c++) {
            int n = c * 16 + ln;
            float bv = bias[n];
            int pk = pk4(acc[c][0] + bv, acc[c][1] + bv, acc[c][2] + bv, acc[c][3] + bv);
            *(int*)(Vb + (((size_t)(sp * 16 + cbase + c) * 64 + q2 * 16 + ln) * 16 + tt * 4)) = pk;
        }
    }
}

// Pass 1: S^T tiles (A=q1 rows = softmax k-dim, B=k2^T cols = att rows).
// p = exp2(acc) via raw v_exp_f32; pk4 over r -> permuted-k fp8 A-entries.
__global__ __launch_bounds__(256) void score_kernel(
        const _Float16* __restrict__ q1sw, const _Float16* __restrict__ k2sw,
        unsigned char* __restrict__ pmat8, float* __restrict__ rowsum) {
    int w = threadIdx.x >> 6, lane = threadIdx.x & 63;
    int quad = lane >> 4, ln = lane & 15;
    int b = blockIdx.z;
    int kL0 = blockIdx.y * 128 + (w & 1) * 64;     // q1 rows (contraction dim of PV)
    int mL0 = blockIdx.x * 128 + (w >> 1) * 64;    // k2 rows (att rows)
    int ltk = ((b << 12) + kL0) >> 4;
    int ltm = ((b << 12) + mL0) >> 4;

    f32x4 acc[4][4];
    #pragma unroll
    for (int i = 0; i < 4; i++)
        #pragma unroll
        for (int j = 0; j < 4; j++) acc[i][j] = f32x4{0.f, 0.f, 0.f, 0.f};

    #pragma unroll
    for (int s = 0; s < 4; s++) {
        half8 a[4], bq[4];
        #pragma unroll
        for (int i = 0; i < 4; i++)
            a[i] = *(const half8*)(q1sw + ((size_t)(((ltk + i) * 4 + s) * 64 + lane)) * 8);
        #pragma unroll
        for (int j = 0; j < 4; j++)
            bq[j] = *(const half8*)(k2sw + ((size_t)(((ltm + j) * 4 + s) * 64 + lane)) * 8);
        #pragma unroll
        for (int i = 0; i < 4; i++)
            #pragma unroll
            for (int j = 0; j < 4; j++)
                acc[i][j] = mfma16(a[i], bq[j], acc[i][j]);
    }

    unsigned char* Pb = pmat8 + (size_t)b * (16u << 20);
    int sp = kL0 >> 6;
    #pragma unroll
    for (int j = 0; j < 4; j++) {
        int4 d;
        float csum = 0.f;
        #pragma unroll
        for (int i = 0; i < 4; i++) {
            float p0 = fexp2(acc[i][j][0]);
            float p1 = fexp2(acc[i][j][1]);
            float p2 = fexp2(acc[i][j][2]);
            float p3 = fexp2(acc[i][j][3]);
            csum += (p0 + p1) + (p2 + p3);
            ((int*)&d)[i] = pk4(p0, p1, p2, p3);
        }
        csum += __shfl_xor(csum, 16);
        csum += __shfl_xor(csum, 32);
        if (lane < 16)
            atomicAdd(&rowsum[(b << 12) + mL0 + j * 16 + ln], csum);
        int lt = (mL0 >> 4) + j;
        *(int4*)(Pb + (((size_t)(lt * 64 + sp)) * 64 + lane) * 16) = d;
    }
}

// Pass 2: O^T = V^T . P^T (operand swap). 512-thread blocks, 8 waves:
// wave (wc, kh) = (n-quarter, k-half). In-block k-split -> 4 waves/SIMD.
// fp32 partials merged in LDS. att-row lands on lane axis.
__global__ __launch_bounds__(512) void pv_kernel(
        const unsigned char* __restrict__ pmat8, const unsigned char* __restrict__ vsw8,
        const float* __restrict__ rowsum,
        _Float16* __restrict__ att1, _Float16* __restrict__ att2) {
    __shared__ f32x4 part[4][2][4][64];   // 32 KB: [wc][m c][n i][lane]
    int w = threadIdx.x >> 6, lane = threadIdx.x & 63;
    int quad = lane >> 4, ln = lane & 15;
    int wc = w & 3, kh = w >> 2;
    int rowG0 = blockIdx.x * 32;
    int b = rowG0 >> 12;
    int lt0 = (rowG0 & (L_ - 1)) >> 4;   // 2 m-tiles
    const unsigned char* Pb = pmat8 + (size_t)b * (16u << 20);
    const unsigned char* Vb = vsw8 + (size_t)b * (1u << 20);
    int c0 = wc * 4;
    int sp0 = kh * 32;

    f32x4 acc[4][2];
    #pragma unroll
    for (int i = 0; i < 4; i++)
        #pragma unroll
        for (int c = 0; c < 2; c++) acc[i][c] = f32x4{0.f, 0.f, 0.f, 0.f};

    lng2 Vf[2][4], Pf[2][2];
    #pragma unroll
    for (int p = 0; p < 2; p++) {
        #pragma unroll
        for (int i = 0; i < 4; i++)
            Vf[p][i] = *(const lng2*)(Vb + (((size_t)((sp0 + p) * 16 + c0 + i)) * 64 + lane) * 16);
        #pragma unroll
        for (int c = 0; c < 2; c++)
            Pf[p][c] = *(const lng2*)(Pb + (((size_t)((lt0 + c) * 64 + sp0 + p)) * 64 + lane) * 16);
    }

    #define PVSTEP(buf, ii) do {                                                     \
        int spn = sp0 + ((((ii) + 2) < 32) ? (ii) + 2 : 31);                         \
        lng2 Vn[4], Pn[2];                                                           \
        _Pragma("unroll")                                                            \
        for (int i = 0; i < 4; i++)                                                  \
            Vn[i] = *(const lng2*)(Vb + (((size_t)(spn * 16 + c0 + i)) * 64 + lane) * 16); \
        _Pragma("unroll")                                                            \
        for (int c = 0; c < 2; c++)                                                  \
            Pn[c] = *(const lng2*)(Pb + (((size_t)((lt0 + c) * 64 + spn)) * 64 + lane) * 16); \
        _Pragma("unroll")                                                            \
        for (int i = 0; i < 4; i++)                                                  \
            _Pragma("unroll")                                                        \
            for (int c = 0; c < 2; c++) {                                            \
                acc[i][c] = mfma8(Vf[buf][i].x, Pf[buf][c].x, acc[i][c]);             \
                acc[i][c] = mfma8(Vf[buf][i].y, Pf[buf][c].y, acc[i][c]);             \
            }                                                                        \
        _Pragma("unroll")                                                            \
        for (int i = 0; i < 4; i++) Vf[buf][i] = Vn[i];                              \
        _Pragma("unroll")                                                            \
        for (int c = 0; c < 2; c++) Pf[buf][c] = Pn[c];                              \
    } while (0)

    for (int ii = 0; ii < 32; ii += 2) {
        PVSTEP(0, ii);
        PVSTEP(1, ii + 1);
    }
    #undef PVSTEP

    if (kh == 1) {
        #pragma unroll
        for (int i = 0; i < 4; i++)
            #pragma unroll
            for (int c = 0; c < 2; c++)
                part[wc][c][i][lane] = acc[i][c];
    }
    __syncthreads();
    if (kh == 0) {
        #pragma unroll
        for (int i = 0; i < 4; i++)
            #pragma unroll
            for (int c = 0; c < 2; c++)
                acc[i][c] += part[wc][c][i][lane];

        _Float16* att = (wc >= 2) ? att2 : att1;
        #pragma unroll
        for (int c = 0; c < 2; c++) {
            float inv = 1.f / rowsum[rowG0 + c * 16 + ln];
            int lt = (rowG0 >> 4) + c;
            #pragma unroll
            for (int sl = 0; sl < 2; sl++) {
                half8 v;
                #pragma unroll
                for (int r = 0; r < 4; r++) {
                    v[r]     = (_Float16)(acc[2 * sl][c][r] * inv);
                    v[r + 4] = (_Float16)(acc[2 * sl + 1][c][r] * inv);
                }
                int s = (wc & 1) * 2 + sl;
                *(half8*)(att + ((size_t)((lt * 4 + s) * 64 + lane)) * 8) = v;
            }
        }
    }
}

// out_s = att_s @ Wp_s + bias + residual ; concat -> res (fp16) ; LNf -> xn (FR fp16)
// 512 blocks x (2 rowtiles x 2 streams).
__global__ __launch_bounds__(256) void attn_out_kernel(const _Float16* att1, const _Float16* att2,
        const _Float16* wsw, const float* bp1, const float* bp2,
        const float* x1, const float* x2, const float* lnf_g, const float* lnf_b,
        _Float16* res, _Float16* xn) {
    __shared__ float sst[2][16][2][2];
    int w = threadIdx.x >> 6, lane = threadIdx.x & 63;
    int quad = lane >> 4, ln = lane & 15;
    int rt = w & 1, st = w >> 1;
    int mbase = blockIdx.x * 32 + rt * 16;
    int lt = mbase >> 4;
    const _Float16* att = st ? att2 : att1;
    const _Float16* Wp = wsw + (st ? WP2_OFF : WP1_OFF);
    const float* bp = st ? bp2 : bp1;
    const float* xres = st ? x2 : x1;

    half8 a[4];
    #pragma unroll
    for (int s = 0; s < 4; s++)
        a[s] = *(const half8*)(att + ((size_t)((lt * 4 + s) * 64 + lane)) * 8);

    f32x4 y[8];
    #pragma unroll
    for (int c = 0; c < 8; c++) y[c] = f32x4{0,0,0,0};

    half8 Wc[4], Wn[4];
    #pragma unroll
    for (int s = 0; s < 4; s++)
        Wc[s] = *(const half8*)(Wp + ((size_t)((s * 8 + 0) * 64 + lane)) * 8);
    #pragma unroll
    for (int c = 0; c < 8; c++) {
        int cn = (c < 7) ? c + 1 : 7;
        #pragma unroll
        for (int s = 0; s < 4; s++)
            Wn[s] = *(const half8*)(Wp + ((size_t)((s * 8 + cn) * 64 + lane)) * 8);
        #pragma unroll
        for (int s = 0; s < 4; s++)
            y[c] = mfma16(a[s], Wc[s], y[c]);
        #pragma unroll
        for (int s = 0; s < 4; s++) Wc[s] = Wn[s];
    }

    float psum[4] = {0,0,0,0}, psq[4] = {0,0,0,0};
    #pragma unroll
    for (int c = 0; c < 8; c++) {
        int n = c * 16 + ln;
        float bv = bp[n];
        #pragma unroll
        for (int r = 0; r < 4; r++) {
            int m = mbase + quad * 4 + r;
            float v = y[c][r] + bv + xres[(size_t)m * D_ + n];
            y[c][r] = v; psum[r] += v; psq[r] += v * v;
        }
    }
    #pragma unroll
    for (int off = 1; off < 16; off <<= 1)
        #pragma unroll
        for (int r = 0; r < 4; r++) { psum[r] += __shfl_xor(psum[r], off); psq[r] += __shfl_xor(psq[r], off); }
    if (ln == 0)
        #pragma unroll
        for (int r = 0; r < 4; r++) {
            sst[rt][quad * 4 + r][st][0] = psum[r];
            sst[rt][quad * 4 + r][st][1] = psq[r];
        }
    __syncthreads();
    #pragma unroll
    for (int r = 0; r < 4; r++) {
        float su = sst[rt][quad * 4 + r][0][0] + sst[rt][quad * 4 + r][1][0];
        float sq = sst[rt][quad * 4 + r][0][1] + sst[rt][quad * 4 + r][1][1];
        float mean = su * (1.f / 256.f);
        float var = sq * (1.f / 256.f) - mean * mean;
        float inv = rsqrtf(var + 1e-5f);
        int m = mbase + quad * 4 + r;
        int lt_m = m >> 4;
        #pragma unroll
        for (int c = 0; c < 8; c++) {
            int colg = st * 128 + c * 16 + ln;
            res[(size_t)m * D2_ + colg] = (_Float16)y[c][r];
            float yn = (y[c][r] - mean) * inv * lnf_g[colg] + lnf_b[colg];
            int s_x = colg >> 5, q_x = (colg >> 3) & 3, j = colg & 7;
            xn[((size_t)((lt_m * 8 + s_x) * 64 + q_x * 16 + (m & 15))) * 8 + j] = (_Float16)yn;
        }
    }
}

// h = gelu(xn @ Wf1 + bf1)  [M x 512], FR in/out. W-prefetch pipeline; fast
// tanh-form GELU (x*sigmoid(2u)) via raw v_exp.
__global__ __launch_bounds__(256) void ffn1_kernel(const _Float16* xn, const _Float16* wsw,
        const float* bf1, _Float16* h) {
    int wave = threadIdx.x >> 6, lane = threadIdx.x & 63;
    int quad = lane >> 4, ln = lane & 15;
    int mbase = blockIdx.x * 64 + wave * 16;
    int lt = mbase >> 4;
    int nt = blockIdx.y;   // 0..3
    const _Float16* W = wsw + WF1_OFF;   // K=256, N=512, nc=32

    half8 a[8];
    #pragma unroll
    for (int s = 0; s < 8; s++)
        a[s] = *(const half8*)(xn + ((size_t)((lt * 8 + s) * 64 + lane)) * 8);

    f32x4 acc[8];
    #pragma unroll
    for (int c = 0; c < 8; c++) acc[c] = f32x4{0,0,0,0};

    half8 Wc[8], Wn[8];
    #pragma unroll
    for (int s = 0; s < 8; s++)
        Wc[s] = *(const half8*)(W + ((size_t)((s * 32 + nt * 8) * 64 + lane)) * 8);
    #pragma unroll
    for (int c = 0; c < 8; c++) {
        int cn = (c < 7) ? c + 1 : 7;
        #pragma unroll
        for (int s = 0; s < 8; s++)
            Wn[s] = *(const half8*)(W + ((size_t)((s * 32 + nt * 8 + cn) * 64 + lane)) * 8);
        #pragma unroll
        for (int s = 0; s < 8; s++)
            acc[c] = mfma16(a[s], Wc[s], acc[c]);
        #pragma unroll
        for (int s = 0; s < 8; s++) Wc[s] = Wn[s];
    }
    #pragma unroll
    for (int c = 0; c < 8; c++) {
        int n = nt * 128 + c * 16 + ln;
        float bv = bf1[n];
        int s_h = n >> 5, q_h = (n >> 3) & 3, j = n & 7;
        #pragma unroll
        for (int r = 0; r < 4; r++) {
            float v = acc[c][r] + bv;
            float u = 0.7978845608f * (v + 0.044715f * v * v * v);
            float e = fexp2(-2.8853900818f * u);     // 2*log2(e)*u
            float ge = v * __builtin_amdgcn_rcpf(1.f + e);
            h[((size_t)((lt * 16 + s_h) * 64 + q_h * 16 + (quad * 4 + r))) * 8 + j] = (_Float16)ge;
        }
    }
}

// FUSED: xn2 = LN3(h @ Wf2 + bf2 + res) -> LDS tile ; out = xn2 @ Wo + bo.
__global__ __launch_bounds__(256) void ffn2_out_kernel(const _Float16* h, const _Float16* wsw,
        const float* bf2, const _Float16* res, const float* g3, const float* b3,
        const float* bo, float* out) {
    __shared__ float sst[2][16][2][2];
    __shared__ _Float16 xt[8192];        // 16 KB: 32 rows x 256 cols, FR layout
    __shared__ f32x4 pc[2][4][64];       // 8 KB: out k-half partials
    int w = threadIdx.x >> 6, lane = threadIdx.x & 63;
    int quad = lane >> 4, ln = lane & 15;
    int rt = w & 1, nh = w >> 1;
    int mb = blockIdx.x * 32 + rt * 16;
    int lt = mb >> 4;
    const _Float16* W = wsw + WF2_OFF;   // K=512, N=256, nc=16

    f32x4 acc[8];
    #pragma unroll
    for (int c = 0; c < 8; c++) acc[c] = f32x4{0,0,0,0};

    half8 aC, aN;
    half8 Wc[8], Wn[8];
    aC = *(const half8*)(h + ((size_t)((lt * 16 + 0) * 64 + lane)) * 8);
    #pragma unroll
    for (int c = 0; c < 8; c++)
        Wc[c] = *(const half8*)(W + ((size_t)((0 * 16 + nh * 8 + c) * 64 + lane)) * 8);

    #pragma unroll
    for (int s = 0; s < 16; s++) {
        int sn = (s < 15) ? s + 1 : 15;
        aN = *(const half8*)(h + ((size_t)((lt * 16 + sn) * 64 + lane)) * 8);
        #pragma unroll
        for (int c = 0; c < 8; c++)
            Wn[c] = *(const half8*)(W + ((size_t)((sn * 16 + nh * 8 + c) * 64 + lane)) * 8);
        #pragma unroll
        for (int c = 0; c < 8; c++)
            acc[c] = mfma16(aC, Wc[c], acc[c]);
        aC = aN;
        #pragma unroll
        for (int c = 0; c < 8; c++) Wc[c] = Wn[c];
    }

    float y[8][4];
    float psum[4] = {0,0,0,0}, psq[4] = {0,0,0,0};
    #pragma unroll
    for (int c = 0; c < 8; c++) {
        int n = nh * 128 + c * 16 + ln;
        float bv = bf2[n];
        #pragma unroll
        for (int r = 0; r < 4; r++) {
            int m = mb + quad * 4 + r;
            float v = acc[c][r] + bv + (float)res[(size_t)m * D2_ + n];
            y[c][r] = v; psum[r] += v; psq[r] += v * v;
        }
    }
    #pragma unroll
    for (int off = 1; off < 16; off <<= 1)
        #pragma unroll
        for (int r = 0; r < 4; r++) { psum[r] += __shfl_xor(psum[r], off); psq[r] += __shfl_xor(psq[r], off); }
    if (ln == 0)
        #pragma unroll
        for (int r = 0; r < 4; r++) { sst[rt][quad * 4 + r][nh][0] = psum[r]; sst[rt][quad * 4 + r][nh][1] = psq[r]; }
    __syncthreads();
    #pragma unroll
    for (int r = 0; r < 4; r++) {
        float su = sst[rt][quad * 4 + r][0][0] + sst[rt][quad * 4 + r][1][0];
        float sq = sst[rt][quad * 4 + r][0][1] + sst[rt][quad * 4 + r][1][1];
        float mean = su * (1.f / 256.f);
        float var = sq * (1.f / 256.f) - mean * mean;
        float invs = rsqrtf(var + 1e-5f);
        #pragma unroll
        for (int c = 0; c < 8; c++) {
            int n = nh * 128 + c * 16 + ln;
            float yn = (y[c][r] - mean) * invs * g3[n] + b3[n];
            int s_x = n >> 5, q_x = (n >> 3) & 3, j = n & 7;
            xt[((rt * 8 + s_x) * 64 + q_x * 16 + (quad * 4 + r)) * 8 + j] = (_Float16)yn;
        }
    }
    __syncthreads();

    // ---- out phase: waves (rt2, kh) ----
    int rt2 = w & 1, kh = w >> 1;
    const _Float16* Wo = wsw + WO_OFF;   // K=256, N=64(padded), nc=4
    f32x4 oacc[4];
    #pragma unroll
    for (int c = 0; c < 4; c++) oacc[c] = f32x4{0,0,0,0};
    #pragma unroll
    for (int ss = 0; ss < 4; ss++) {
        int s = kh * 4 + ss;
        half8 a = *(const half8*)(xt + ((size_t)((rt2 * 8 + s) * 64 + lane)) * 8);
        #pragma unroll
        for (int c = 0; c < 4; c++)
            oacc[c] = mfma16(a, *(const half8*)(Wo + ((size_t)((s * 4 + c) * 64 + lane)) * 8), oacc[c]);
    }
    if (kh == 1)
        #pragma unroll
        for (int c = 0; c < 4; c++) pc[rt2][c][lane] = oacc[c];
    __syncthreads();
    if (kh == 0) {
        int mb2 = blockIdx.x * 32 + rt2 * 16;
        #pragma unroll
        for (int c = 0; c < 4; c++) {
            f32x4 p = pc[rt2][c][lane];
            int n = c * 16 + ln;
            if (n < OUT_) {
                float bv = bo[n];
                #pragma unroll
                for (int r = 0; r < 4; r++)
                    out[(size_t)(mb2 + quad * 4 + r) * OUT_ + n] = oacc[c][r] + p[r] + bv;
            }
        }
    }
}

extern "C" void kernel_launch(void* const* d_in, const int* in_sizes, int n_in,
                              void* d_out, int out_size, void* d_ws, size_t ws_size,
                              hipStream_t stream) {
    const float* x1    = (const float*)d_in[0];
    const float* x2    = (const float*)d_in[1];
    const float* ln1_g = (const float*)d_in[2];
    const float* ln1_b = (const float*)d_in[3];
    const float* ln2_g = (const float*)d_in[4];
    const float* ln2_b = (const float*)d_in[5];
    const float* Wq    = (const float*)d_in[6];
    const float* bq    = (const float*)d_in[7];
    const float* Wv1   = (const float*)d_in[8];
    const float* bv1   = (const float*)d_in[9];
    const float* Wk    = (const float*)d_in[10];
    const float* bk    = (const float*)d_in[11];
    const float* Wv2   = (const float*)d_in[12];
    const float* bv2   = (const float*)d_in[13];
    const float* Wp1   = (const float*)d_in[14];
    const float* bp1   = (const float*)d_in[15];
    const float* Wp2   = (const float*)d_in[16];
    const float* bp2   = (const float*)d_in[17];
    const float* lnf_g = (const float*)d_in[18];
    const float* lnf_b = (const float*)d_in[19];
    const float* Wf1   = (const float*)d_in[20];
    const float* bf1   = (const float*)d_in[21];
    const float* Wf2   = (const float*)d_in[22];
    const float* bf2   = (const float*)d_in[23];
    const float* ln3_g = (const float*)d_in[24];
    const float* ln3_b = (const float*)d_in[25];
    const float* Wo    = (const float*)d_in[26];
    const float* bo    = (const float*)d_in[27];
    float* out = (float*)d_out;

    char* ws = (char*)d_ws;
    const size_t MB = 1 << 20;
    _Float16* q1sw   = (_Float16*)(ws + 0 * MB);    // 4 MB
    _Float16* k2sw   = (_Float16*)(ws + 4 * MB);    // 4 MB
    unsigned char* vsw8 = (unsigned char*)(ws + 8 * MB);   // 4 MB (fp8 Vcat per batch)
    _Float16* att1   = (_Float16*)(ws + 12 * MB);   // 4 MB
    _Float16* att2   = (_Float16*)(ws + 16 * MB);   // 4 MB
    _Float16* wsw    = (_Float16*)(ws + 28 * MB);   // ~0.74 MB
    float*    rowsum = (float*)   (ws + 29 * MB);   // 64 KB
    _Float16* res    = (_Float16*)(ws + 30 * MB);   // 8 MB
    _Float16* xn     = (_Float16*)(ws + 46 * MB);   // 8 MB
    _Float16* h      = (_Float16*)(ws + 54 * MB);   // 16 MB
    unsigned char* pmat8 = (unsigned char*)(ws + 78 * MB); // 64 MB (fp8 P per batch)

    prep_kernel<<<dim3(512, 10), 256, 0, stream>>>(Wq, Wv1, Wk, Wv2, Wp1, Wp2, Wf1, Wf2, Wo,
                                                   wsw, rowsum);
    proj_kernel<<<dim3(M_ / 64, 4), 256, 0, stream>>>(x1, x2, wsw,
                                                      ln1_g, ln1_b, ln2_g, ln2_b,
                                                      bq, bv1, bk, bv2,
                                                      q1sw, k2sw, vsw8);
    score_kernel<<<dim3(32, 32, 4), 256, 0, stream>>>(q1sw, k2sw, pmat8, rowsum);
    pv_kernel<<<dim3(M_ / 32), 512, 0, stream>>>(pmat8, vsw8, rowsum, att1, att2);
    attn_out_kernel<<<dim3(M_ / 32), 256, 0, stream>>>(att1, att2, wsw, bp1, bp2,
                                                       x1, x2, lnf_g, lnf_b, res, xn);
    ffn1_kernel<<<dim3(M_ / 64, 4), 256, 0, stream>>>(xn, wsw, bf1, h);
    ffn2_out_kernel<<<dim3(M_ / 32), 256, 0, stream>>>(h, wsw, bf2, res, ln3_g, ln3_b, bo, out);
}

// Round 16
// 232.797 us; speedup vs baseline: 1.4071x; 1.0012x over previous
//
#include <hip/hip_runtime.h>
#include <hip/hip_fp16.h>

typedef _Float16 half8 __attribute__((ext_vector_type(8)));
typedef float f32x4 __attribute__((ext_vector_type(4)));
typedef long lng2 __attribute__((ext_vector_type(2)));

#define B_   4
#define L_   4096
#define D_   128
#define M_   (B_*L_)     // 16384
#define D2_  256
#define H_   512
#define OUT_ 55

__device__ __forceinline__ f32x4 mfma16(half8 a, half8 b, f32x4 c) {
    return __builtin_amdgcn_mfma_f32_16x16x32_f16(a, b, c, 0, 0, 0);
}
__device__ __forceinline__ f32x4 mfma8(long a, long b, f32x4 c) {
    return __builtin_amdgcn_mfma_f32_16x16x32_fp8_fp8(a, b, c, 0, 0, 0);
}
// pack 4 floats -> 4 fp8 e4m3 bytes (OCP on gfx950)
__device__ __forceinline__ int pk4(float a, float b, float c, float d) {
    int t = __builtin_amdgcn_cvt_pk_fp8_f32(a, b, 0, false);
    return __builtin_amdgcn_cvt_pk_fp8_f32(c, d, t, true);
}
// raw v_exp_f32 — exp2f w/o fast-math lowers to OCML denorm-safe seq (~25cyc, r8 VALUBusy=47%)
__device__ __forceinline__ float fexp2(float x) { return __builtin_amdgcn_exp2f(x); }

// fold softmax scale (1/sqrt(128)) * log2(e) into k2 so score uses bare v_exp
#define KSCL (0.08838834764831845f * 1.4426950408889634f)

// ---- weight swizzle offsets (in halfs) within wsw region ----
#define WQ_OFF   0
#define WV1_OFF  16384
#define WK_OFF   32768
#define WV2_OFF  49152
#define WP1_OFF  65536
#define WP2_OFF  81920
#define WF1_OFF  98304     // 256x512 = 131072
#define WF2_OFF  229376    // 512x256 = 131072
#define WO_OFF   360448    // 256x64 (padded) = 16384

// Permuted k-map (within a 32-k chunk): k5 = (h<4 ? q*4+h : 16+q*4+(h-4)).
// Used for fp8 P & V and fp16 att & Wp1/Wp2 — A/B agree pairwise.
// NOTE (r13): score+pv fusion with LDS-resident P regressed 239->328 us —
// 16-row m-tiles re-read full q1+V per block (2 GB L2 traffic vs 128 MB P
// round-trip). P-through-memory two-pass is structurally better here.

// Pre-swizzle weights (fp32 row-major [K][N]) into B-fragment layout fp16.
// canonical: q=(k>>3)&3, j=k&7 ; permK (Wp1/Wp2 only): q=(k>>2)&3, j=(k&3)+4*((k>>4)&1)
// id==9: zero the rowsum buffer (absorbed zero_kernel — one less launch).
__global__ void prep_kernel(const float* Wq, const float* Wv1, const float* Wk,
                            const float* Wv2, const float* Wp1, const float* Wp2,
                            const float* Wf1, const float* Wf2, const float* Wo,
                            _Float16* wsw, float* rowsum) {
    int id = blockIdx.y;
    int t  = blockIdx.x * 256 + threadIdx.x;
    if (id == 9) {
        if (t < 4096) ((f32x4*)rowsum)[t] = f32x4{0.f, 0.f, 0.f, 0.f};
        return;
    }
    const float* src = nullptr; int K = 0, N = 0, Npad = 0, off = 0;
    switch (id) {
        case 0: src = Wq;  K = 128; N = 128; Npad = 128; off = WQ_OFF;  break;
        case 1: src = Wv1; K = 128; N = 128; Npad = 128; off = WV1_OFF; break;
        case 2: src = Wk;  K = 128; N = 128; Npad = 128; off = WK_OFF;  break;
        case 3: src = Wv2; K = 128; N = 128; Npad = 128; off = WV2_OFF; break;
        case 4: src = Wp1; K = 128; N = 128; Npad = 128; off = WP1_OFF; break;
        case 5: src = Wp2; K = 128; N = 128; Npad = 128; off = WP2_OFF; break;
        case 6: src = Wf1; K = 256; N = 512; Npad = 512; off = WF1_OFF; break;
        case 7: src = Wf2; K = 512; N = 256; Npad = 256; off = WF2_OFF; break;
        case 8: src = Wo;  K = 256; N = 55;  Npad = 64;  off = WO_OFF;  break;
        default: return;
    }
    int total = K * Npad;
    if (t >= total) return;
    int k = t / Npad, n = t % Npad;
    float v = (n < N) ? src[k * N + n] : 0.f;
    int s = k >> 5, c = n >> 4, ln = n & 15;
    int q, j;
    if (id == 4 || id == 5) { q = (k >> 2) & 3; j = (k & 3) + (((k >> 4) & 1) << 2); }
    else                    { q = (k >> 3) & 3; j = k & 7; }
    int nc = Npad >> 4;
    wsw[off + ((size_t)((s * nc + c) * 64 + q * 16 + ln)) * 8 + j] = (_Float16)v;
}

// FR layout for X[M][C] halfs:
// idx = ((lt*(C/32) + s)*64 + q*16 + ln_r)*8 + j ; lt=row>>4, ln_r=row&15,
// s=col>>5, q=(col>>3)&3, j=col&7.

// Projections with fused input LayerNorm, BOTH weight-groups per stream in one
// block (r16: grid y 4->2 — LN computed once, X L2 traffic halved).
// Pipeline 0: Wq->q1 FR (stream 1) / Wk->k2 FR *KSCL (stream 2).
// Pipeline 1: Wv1/Wv2 -> vsw8 fp8 permuted-k B-frag layout.
__global__ __launch_bounds__(256) void proj_kernel(const float* x1, const float* x2,
        const _Float16* wsw,
        const float* ln1_g, const float* ln1_b, const float* ln2_g, const float* ln2_b,
        const float* bq, const float* bv1, const float* bk, const float* bv2,
        _Float16* q1, _Float16* k2, unsigned char* vsw8) {
    int g2 = blockIdx.y;  // 0: stream 1, 1: stream 2
    const float* X  = g2 ? x2 : x1;
    const float* lg = g2 ? ln2_g : ln1_g;
    const float* lb = g2 ? ln2_b : ln1_b;
    int wave = threadIdx.x >> 6, lane = threadIdx.x & 63;
    int quad = lane >> 4, ln = lane & 15;
    int mbase = blockIdx.x * 64 + wave * 16;
    int lt = mbase >> 4;

    // ---- fused LN: this lane holds row (mbase+ln), cols s*32+quad*8..+7 ----
    const float* xr = X + (size_t)(mbase + ln) * D_;
    float xv[4][8];
    float sum = 0.f, sq = 0.f;
    #pragma unroll
    for (int s = 0; s < 4; s++) {
        f32x4 v0 = *(const f32x4*)(xr + s * 32 + quad * 8);
        f32x4 v1 = *(const f32x4*)(xr + s * 32 + quad * 8 + 4);
        #pragma unroll
        for (int j = 0; j < 4; j++) {
            xv[s][j]     = v0[j];
            xv[s][j + 4] = v1[j];
            sum += v0[j] + v1[j];
            sq  += v0[j] * v0[j] + v1[j] * v1[j];
        }
    }
    // rows are striped across lanes {ln, ln+16, ln+32, ln+48}
    sum += __shfl_xor(sum, 16); sum += __shfl_xor(sum, 32);
    sq  += __shfl_xor(sq, 16);  sq  += __shfl_xor(sq, 32);
    float mean = sum * (1.f / 128.f);
    float var  = sq * (1.f / 128.f) - mean * mean;
    float inv  = rsqrtf(var + 1e-5f);
    half8 a[4];
    #pragma unroll
    for (int s = 0; s < 4; s++) {
        f32x4 g0 = *(const f32x4*)(lg + s * 32 + quad * 8);
        f32x4 g1 = *(const f32x4*)(lg + s * 32 + quad * 8 + 4);
        f32x4 b0 = *(const f32x4*)(lb + s * 32 + quad * 8);
        f32x4 b1 = *(const f32x4*)(lb + s * 32 + quad * 8 + 4);
        #pragma unroll
        for (int j = 0; j < 4; j++) {
            a[s][j]     = (_Float16)((xv[s][j] - mean) * inv * g0[j] + b0[j]);
            a[s][j + 4] = (_Float16)((xv[s][j + 4] - mean) * inv * g1[j] + b1[j]);
        }
    }

    // ---- pipeline 0: Q/K projection -> fp16 FR ----
    {
        const _Float16* Bw = wsw + (g2 ? WK_OFF : WQ_OFF);
        const float* bias = g2 ? bk : bq;
        float scl = g2 ? KSCL : 1.f;
        _Float16* out = g2 ? k2 : q1;
        f32x4 acc[8];
        #pragma unroll
        for (int c = 0; c < 8; c++) acc[c] = f32x4{0.f, 0.f, 0.f, 0.f};
        half8 Wc[4], Wn[4];
        #pragma unroll
        for (int s = 0; s < 4; s++)
            Wc[s] = *(const half8*)(Bw + ((size_t)((s * 8 + 0) * 64 + lane)) * 8);
        #pragma unroll
        for (int c = 0; c < 8; c++) {
            int cn = (c < 7) ? c + 1 : 7;
            #pragma unroll
            for (int s = 0; s < 4; s++)
                Wn[s] = *(const half8*)(Bw + ((size_t)((s * 8 + cn) * 64 + lane)) * 8);
            #pragma unroll
            for (int s = 0; s < 4; s++)
                acc[c] = mfma16(a[s], Wc[s], acc[c]);
            #pragma unroll
            for (int s = 0; s < 4; s++) Wc[s] = Wn[s];
        }
        #pragma unroll
        for (int c = 0; c < 8; c++) {
            int n = c * 16 + ln;
            float bv = bias[n];
            #pragma unroll
            for (int r = 0; r < 4; r++) {
                int s_o = c >> 1, q_o = ((c & 1) << 1) | (ln >> 3), j = ln & 7;
                out[((size_t)((lt * 4 + s_o) * 64 + q_o * 16 + (quad * 4 + r))) * 8 + j]
                    = (_Float16)((acc[c][r] + bv) * scl);
            }
        }
    }

    // ---- pipeline 1: V projection -> fp8 permuted-k B-frag ----
    {
        const _Float16* Bw = wsw + (g2 ? WV2_OFF : WV1_OFF);
        const float* bias = g2 ? bv2 : bv1;
        int cbase = g2 ? 8 : 0;
        f32x4 acc[8];
        #pragma unroll
        for (int c = 0; c < 8; c++) acc[c] = f32x4{0.f, 0.f, 0.f, 0.f};
        half8 Wc[4], Wn[4];
        #pragma unroll
        for (int s = 0; s < 4; s++)
            Wc[s] = *(const half8*)(Bw + ((size_t)((s * 8 + 0) * 64 + lane)) * 8);
        #pragma unroll
        for (int c = 0; c < 8; c++) {
            int cn = (c < 7) ? c + 1 : 7;
            #pragma unroll
            for (int s = 0; s < 4; s++)
                Wn[s] = *(const half8*)(Bw + ((size_t)((s * 8 + cn) * 64 + lane)) * 8);
            #pragma unroll
            for (int s = 0; s < 4; s++)
                acc[c] = mfma16(a[s], Wc[s], acc[c]);
            #pragma unroll
            for (int s = 0; s < 4; s++) Wc[s] = Wn[s];
        }
        int b = mbase >> 12;
        int l0 = (mbase & (L_ - 1)) + quad * 4;
        int sp = l0 >> 6, tt = (l0 >> 4) & 3, q2 = (l0 >> 2) & 3;
        unsigned char* Vb = vsw8 + (size_t)b * (1u << 20);
        #pragma unroll
        for (int c = 0; c < 8; c++) {
            int n = c * 16 + ln;
            float bv = bias[n];
            int pk = pk4(acc[c][0] + bv, acc[c][1] + bv, acc[c][2] + bv, acc[c][3] + bv);
            *(int*)(Vb + (((size_t)(sp * 16 + cbase + c) * 64 + q2 * 16 + ln) * 16 + tt * 4)) = pk;
        }
    }
}

// Pass 1: S^T tiles (A=q1 rows = softmax k-dim, B=k2^T cols = att rows).
// p = exp2(acc) via raw v_exp_f32; pk4 over r -> permuted-k fp8 A-entries.
__global__ __launch_bounds__(256) void score_kernel(
        const _Float16* __restrict__ q1sw, const _Float16* __restrict__ k2sw,
        unsigned char* __restrict__ pmat8, float* __restrict__ rowsum) {
    int w = threadIdx.x >> 6, lane = threadIdx.x & 63;
    int quad = lane >> 4, ln = lane & 15;
    int b = blockIdx.z;
    int kL0 = blockIdx.y * 128 + (w & 1) * 64;     // q1 rows (contraction dim of PV)
    int mL0 = blockIdx.x * 128 + (w >> 1) * 64;    // k2 rows (att rows)
    int ltk = ((b << 12) + kL0) >> 4;
    int ltm = ((b << 12) + mL0) >> 4;

    f32x4 acc[4][4];
    #pragma unroll
    for (int i = 0; i < 4; i++)
        #pragma unroll
        for (int j = 0; j < 4; j++) acc[i][j] = f32x4{0.f, 0.f, 0.f, 0.f};

    #pragma unroll
    for (int s = 0; s < 4; s++) {
        half8 a[4], bq[4];
        #pragma unroll
        for (int i = 0; i < 4; i++)
            a[i] = *(const half8*)(q1sw + ((size_t)(((ltk + i) * 4 + s) * 64 + lane)) * 8);
        #pragma unroll
        for (int j = 0; j < 4; j++)
            bq[j] = *(const half8*)(k2sw + ((size_t)(((ltm + j) * 4 + s) * 64 + lane)) * 8);
        #pragma unroll
        for (int i = 0; i < 4; i++)
            #pragma unroll
            for (int j = 0; j < 4; j++)
                acc[i][j] = mfma16(a[i], bq[j], acc[i][j]);
    }

    unsigned char* Pb = pmat8 + (size_t)b * (16u << 20);
    int sp = kL0 >> 6;
    #pragma unroll
    for (int j = 0; j < 4; j++) {
        int4 d;
        float csum = 0.f;
        #pragma unroll
        for (int i = 0; i < 4; i++) {
            float p0 = fexp2(acc[i][j][0]);
            float p1 = fexp2(acc[i][j][1]);
            float p2 = fexp2(acc[i][j][2]);
            float p3 = fexp2(acc[i][j][3]);
            csum += (p0 + p1) + (p2 + p3);
            ((int*)&d)[i] = pk4(p0, p1, p2, p3);
        }
        csum += __shfl_xor(csum, 16);
        csum += __shfl_xor(csum, 32);
        if (lane < 16)
            atomicAdd(&rowsum[(b << 12) + mL0 + j * 16 + ln], csum);
        int lt = (mL0 >> 4) + j;
        *(int4*)(Pb + (((size_t)(lt * 64 + sp)) * 64 + lane) * 16) = d;
    }
}

// Pass 2: O^T = V^T . P^T (operand swap). 512-thread blocks, 8 waves:
// wave (wc, kh) = (n-quarter, k-half). In-block k-split -> 4 waves/SIMD.
// fp32 partials merged in LDS. att-row lands on lane axis.
__global__ __launch_bounds__(512) void pv_kernel(
        const unsigned char* __restrict__ pmat8, const unsigned char* __restrict__ vsw8,
        const float* __restrict__ rowsum,
        _Float16* __restrict__ att1, _Float16* __restrict__ att2) {
    __shared__ f32x4 part[4][2][4][64];   // 32 KB: [wc][m c][n i][lane]
    int w = threadIdx.x >> 6, lane = threadIdx.x & 63;
    int quad = lane >> 4, ln = lane & 15;
    int wc = w & 3, kh = w >> 2;
    int rowG0 = blockIdx.x * 32;
    int b = rowG0 >> 12;
    int lt0 = (rowG0 & (L_ - 1)) >> 4;   // 2 m-tiles
    const unsigned char* Pb = pmat8 + (size_t)b * (16u << 20);
    const unsigned char* Vb = vsw8 + (size_t)b * (1u << 20);
    int c0 = wc * 4;
    int sp0 = kh * 32;

    f32x4 acc[4][2];
    #pragma unroll
    for (int i = 0; i < 4; i++)
        #pragma unroll
        for (int c = 0; c < 2; c++) acc[i][c] = f32x4{0.f, 0.f, 0.f, 0.f};

    lng2 Vf[2][4], Pf[2][2];
    #pragma unroll
    for (int p = 0; p < 2; p++) {
        #pragma unroll
        for (int i = 0; i < 4; i++)
            Vf[p][i] = *(const lng2*)(Vb + (((size_t)((sp0 + p) * 16 + c0 + i)) * 64 + lane) * 16);
        #pragma unroll
        for (int c = 0; c < 2; c++)
            Pf[p][c] = *(const lng2*)(Pb + (((size_t)((lt0 + c) * 64 + sp0 + p)) * 64 + lane) * 16);
    }

    #define PVSTEP(buf, ii) do {                                                     \
        int spn = sp0 + ((((ii) + 2) < 32) ? (ii) + 2 : 31);                         \
        lng2 Vn[4], Pn[2];                                                           \
        _Pragma("unroll")                                                            \
        for (int i = 0; i < 4; i++)                                                  \
            Vn[i] = *(const lng2*)(Vb + (((size_t)(spn * 16 + c0 + i)) * 64 + lane) * 16); \
        _Pragma("unroll")                                                            \
        for (int c = 0; c < 2; c++)                                                  \
            Pn[c] = *(const lng2*)(Pb + (((size_t)((lt0 + c) * 64 + spn)) * 64 + lane) * 16); \
        _Pragma("unroll")                                                            \
        for (int i = 0; i < 4; i++)                                                  \
            _Pragma("unroll")                                                        \
            for (int c = 0; c < 2; c++) {                                            \
                acc[i][c] = mfma8(Vf[buf][i].x, Pf[buf][c].x, acc[i][c]);             \
                acc[i][c] = mfma8(Vf[buf][i].y, Pf[buf][c].y, acc[i][c]);             \
            }                                                                        \
        _Pragma("unroll")                                                            \
        for (int i = 0; i < 4; i++) Vf[buf][i] = Vn[i];                              \
        _Pragma("unroll")                                                            \
        for (int c = 0; c < 2; c++) Pf[buf][c] = Pn[c];                              \
    } while (0)

    for (int ii = 0; ii < 32; ii += 2) {
        PVSTEP(0, ii);
        PVSTEP(1, ii + 1);
    }
    #undef PVSTEP

    if (kh == 1) {
        #pragma unroll
        for (int i = 0; i < 4; i++)
            #pragma unroll
            for (int c = 0; c < 2; c++)
                part[wc][c][i][lane] = acc[i][c];
    }
    __syncthreads();
    if (kh == 0) {
        #pragma unroll
        for (int i = 0; i < 4; i++)
            #pragma unroll
            for (int c = 0; c < 2; c++)
                acc[i][c] += part[wc][c][i][lane];

        _Float16* att = (wc >= 2) ? att2 : att1;
        #pragma unroll
        for (int c = 0; c < 2; c++) {
            float inv = 1.f / rowsum[rowG0 + c * 16 + ln];
            int lt = (rowG0 >> 4) + c;
            #pragma unroll
            for (int sl = 0; sl < 2; sl++) {
                half8 v;
                #pragma unroll
                for (int r = 0; r < 4; r++) {
                    v[r]     = (_Float16)(acc[2 * sl][c][r] * inv);
                    v[r + 4] = (_Float16)(acc[2 * sl + 1][c][r] * inv);
                }
                int s = (wc & 1) * 2 + sl;
                *(half8*)(att + ((size_t)((lt * 4 + s) * 64 + lane)) * 8) = v;
            }
        }
    }
}

// out_s = att_s @ Wp_s + bias + residual ; concat -> res (fp16) ; LNf -> xn (FR fp16)
// 512 blocks x (2 rowtiles x 2 streams).
__global__ __launch_bounds__(256) void attn_out_kernel(const _Float16* att1, const _Float16* att2,
        const _Float16* wsw, const float* bp1, const float* bp2,
        const float* x1, const float* x2, const float* lnf_g, const float* lnf_b,
        _Float16* res, _Float16* xn) {
    __shared__ float sst[2][16][2][2];
    int w = threadIdx.x >> 6, lane = threadIdx.x & 63;
    int quad = lane >> 4, ln = lane & 15;
    int rt = w & 1, st = w >> 1;
    int mbase = blockIdx.x * 32 + rt * 16;
    int lt = mbase >> 4;
    const _Float16* att = st ? att2 : att1;
    const _Float16* Wp = wsw + (st ? WP2_OFF : WP1_OFF);
    const float* bp = st ? bp2 : bp1;
    const float* xres = st ? x2 : x1;

    half8 a[4];
    #pragma unroll
    for (int s = 0; s < 4; s++)
        a[s] = *(const half8*)(att + ((size_t)((lt * 4 + s) * 64 + lane)) * 8);

    f32x4 y[8];
    #pragma unroll
    for (int c = 0; c < 8; c++) y[c] = f32x4{0,0,0,0};

    half8 Wc[4], Wn[4];
    #pragma unroll
    for (int s = 0; s < 4; s++)
        Wc[s] = *(const half8*)(Wp + ((size_t)((s * 8 + 0) * 64 + lane)) * 8);
    #pragma unroll
    for (int c = 0; c < 8; c++) {
        int cn = (c < 7) ? c + 1 : 7;
        #pragma unroll
        for (int s = 0; s < 4; s++)
            Wn[s] = *(const half8*)(Wp + ((size_t)((s * 8 + cn) * 64 + lane)) * 8);
        #pragma unroll
        for (int s = 0; s < 4; s++)
            y[c] = mfma16(a[s], Wc[s], y[c]);
        #pragma unroll
        for (int s = 0; s < 4; s++) Wc[s] = Wn[s];
    }

    float psum[4] = {0,0,0,0}, psq[4] = {0,0,0,0};
    #pragma unroll
    for (int c = 0; c < 8; c++) {
        int n = c * 16 + ln;
        float bv = bp[n];
        #pragma unroll
        for (int r = 0; r < 4; r++) {
            int m = mbase + quad * 4 + r;
            float v = y[c][r] + bv + xres[(size_t)m * D_ + n];
            y[c][r] = v; psum[r] += v; psq[r] += v * v;
        }
    }
    #pragma unroll
    for (int off = 1; off < 16; off <<= 1)
        #pragma unroll
        for (int r = 0; r < 4; r++) { psum[r] += __shfl_xor(psum[r], off); psq[r] += __shfl_xor(psq[r], off); }
    if (ln == 0)
        #pragma unroll
        for (int r = 0; r < 4; r++) {
            sst[rt][quad * 4 + r][st][0] = psum[r];
            sst[rt][quad * 4 + r][st][1] = psq[r];
        }
    __syncthreads();
    #pragma unroll
    for (int r = 0; r < 4; r++) {
        float su = sst[rt][quad * 4 + r][0][0] + sst[rt][quad * 4 + r][1][0];
        float sq = sst[rt][quad * 4 + r][0][1] + sst[rt][quad * 4 + r][1][1];
        float mean = su * (1.f / 256.f);
        float var = sq * (1.f / 256.f) - mean * mean;
        float inv = rsqrtf(var + 1e-5f);
        int m = mbase + quad * 4 + r;
        int lt_m = m >> 4;
        #pragma unroll
        for (int c = 0; c < 8; c++) {
            int colg = st * 128 + c * 16 + ln;
            res[(size_t)m * D2_ + colg] = (_Float16)y[c][r];
            float yn = (y[c][r] - mean) * inv * lnf_g[colg] + lnf_b[colg];
            int s_x = colg >> 5, q_x = (colg >> 3) & 3, j = colg & 7;
            xn[((size_t)((lt_m * 8 + s_x) * 64 + q_x * 16 + (m & 15))) * 8 + j] = (_Float16)yn;
        }
    }
}

// h = gelu(xn @ Wf1 + bf1)  [M x 512], FR in/out. W-prefetch pipeline; fast
// tanh-form GELU (x*sigmoid(2u)) via raw v_exp.
__global__ __launch_bounds__(256) void ffn1_kernel(const _Float16* xn, const _Float16* wsw,
        const float* bf1, _Float16* h) {
    int wave = threadIdx.x >> 6, lane = threadIdx.x & 63;
    int quad = lane >> 4, ln = lane & 15;
    int mbase = blockIdx.x * 64 + wave * 16;
    int lt = mbase >> 4;
    int nt = blockIdx.y;   // 0..3
    const _Float16* W = wsw + WF1_OFF;   // K=256, N=512, nc=32

    half8 a[8];
    #pragma unroll
    for (int s = 0; s < 8; s++)
        a[s] = *(const half8*)(xn + ((size_t)((lt * 8 + s) * 64 + lane)) * 8);

    f32x4 acc[8];
    #pragma unroll
    for (int c = 0; c < 8; c++) acc[c] = f32x4{0,0,0,0};

    half8 Wc[8], Wn[8];
    #pragma unroll
    for (int s = 0; s < 8; s++)
        Wc[s] = *(const half8*)(W + ((size_t)((s * 32 + nt * 8) * 64 + lane)) * 8);
    #pragma unroll
    for (int c = 0; c < 8; c++) {
        int cn = (c < 7) ? c + 1 : 7;
        #pragma unroll
        for (int s = 0; s < 8; s++)
            Wn[s] = *(const half8*)(W + ((size_t)((s * 32 + nt * 8 + cn) * 64 + lane)) * 8);
        #pragma unroll
        for (int s = 0; s < 8; s++)
            acc[c] = mfma16(a[s], Wc[s], acc[c]);
        #pragma unroll
        for (int s = 0; s < 8; s++) Wc[s] = Wn[s];
    }
    #pragma unroll
    for (int c = 0; c < 8; c++) {
        int n = nt * 128 + c * 16 + ln;
        float bv = bf1[n];
        int s_h = n >> 5, q_h = (n >> 3) & 3, j = n & 7;
        #pragma unroll
        for (int r = 0; r < 4; r++) {
            float v = acc[c][r] + bv;
            float u = 0.7978845608f * (v + 0.044715f * v * v * v);
            float e = fexp2(-2.8853900818f * u);     // 2*log2(e)*u
            float ge = v * __builtin_amdgcn_rcpf(1.f + e);
            h[((size_t)((lt * 16 + s_h) * 64 + q_h * 16 + (quad * 4 + r))) * 8 + j] = (_Float16)ge;
        }
    }
}

// FUSED: xn2 = LN3(h @ Wf2 + bf2 + res) -> LDS tile ; out = xn2 @ Wo + bo.
__global__ __launch_bounds__(256) void ffn2_out_kernel(const _Float16* h, const _Float16* wsw,
        const float* bf2, const _Float16* res, const float* g3, const float* b3,
        const float* bo, float* out) {
    __shared__ float sst[2][16][2][2];
    __shared__ _Float16 xt[8192];        // 16 KB: 32 rows x 256 cols, FR layout
    __shared__ f32x4 pc[2][4][64];       // 8 KB: out k-half partials
    int w = threadIdx.x >> 6, lane = threadIdx.x & 63;
    int quad = lane >> 4, ln = lane & 15;
    int rt = w & 1, nh = w >> 1;
    int mb = blockIdx.x * 32 + rt * 16;
    int lt = mb >> 4;
    const _Float16* W = wsw + WF2_OFF;   // K=512, N=256, nc=16

    f32x4 acc[8];
    #pragma unroll
    for (int c = 0; c < 8; c++) acc[c] = f32x4{0,0,0,0};

    half8 aC, aN;
    half8 Wc[8], Wn[8];
    aC = *(const half8*)(h + ((size_t)((lt * 16 + 0) * 64 + lane)) * 8);
    #pragma unroll
    for (int c = 0; c < 8; c++)
        Wc[c] = *(const half8*)(W + ((size_t)((0 * 16 + nh * 8 + c) * 64 + lane)) * 8);

    #pragma unroll
    for (int s = 0; s < 16; s++) {
        int sn = (s < 15) ? s + 1 : 15;
        aN = *(const half8*)(h + ((size_t)((lt * 16 + sn) * 64 + lane)) * 8);
        #pragma unroll
        for (int c = 0; c < 8; c++)
            Wn[c] = *(const half8*)(W + ((size_t)((sn * 16 + nh * 8 + c) * 64 + lane)) * 8);
        #pragma unroll
        for (int c = 0; c < 8; c++)
            acc[c] = mfma16(aC, Wc[c], acc[c]);
        aC = aN;
        #pragma unroll
        for (int c = 0; c < 8; c++) Wc[c] = Wn[c];
    }

    float y[8][4];
    float psum[4] = {0,0,0,0}, psq[4] = {0,0,0,0};
    #pragma unroll
    for (int c = 0; c < 8; c++) {
        int n = nh * 128 + c * 16 + ln;
        float bv = bf2[n];
        #pragma unroll
        for (int r = 0; r < 4; r++) {
            int m = mb + quad * 4 + r;
            float v = acc[c][r] + bv + (float)res[(size_t)m * D2_ + n];
            y[c][r] = v; psum[r] += v; psq[r] += v * v;
        }
    }
    #pragma unroll
    for (int off = 1; off < 16; off <<= 1)
        #pragma unroll
        for (int r = 0; r < 4; r++) { psum[r] += __shfl_xor(psum[r], off); psq[r] += __shfl_xor(psq[r], off); }
    if (ln == 0)
        #pragma unroll
        for (int r = 0; r < 4; r++) { sst[rt][quad * 4 + r][nh][0] = psum[r]; sst[rt][quad * 4 + r][nh][1] = psq[r]; }
    __syncthreads();
    #pragma unroll
    for (int r = 0; r < 4; r++) {
        float su = sst[rt][quad * 4 + r][0][0] + sst[rt][quad * 4 + r][1][0];
        float sq = sst[rt][quad * 4 + r][0][1] + sst[rt][quad * 4 + r][1][1];
        float mean = su * (1.f / 256.f);
        float var = sq * (1.f / 256.f) - mean * mean;
        float invs = rsqrtf(var + 1e-5f);
        #pragma unroll
        for (int c = 0; c < 8; c++) {
            int n = nh * 128 + c * 16 + ln;
            float yn = (y[c][r] - mean) * invs * g3[n] + b3[n];
            int s_x = n >> 5, q_x = (n >> 3) & 3, j = n & 7;
            xt[((rt * 8 + s_x) * 64 + q_x * 16 + (quad * 4 + r)) * 8 + j] = (_Float16)yn;
        }
    }
    __syncthreads();

    // ---- out phase: waves (rt2, kh) ----
    int rt2 = w & 1, kh = w >> 1;
    const _Float16* Wo = wsw + WO_OFF;   // K=256, N=64(padded), nc=4
    f32x4 oacc[4];
    #pragma unroll
    for (int c = 0; c < 4; c++) oacc[c] = f32x4{0,0,0,0};
    #pragma unroll
    for (int ss = 0; ss < 4; ss++) {
        int s = kh * 4 + ss;
        half8 a = *(const half8*)(xt + ((size_t)((rt2 * 8 + s) * 64 + lane)) * 8);
        #pragma unroll
        for (int c = 0; c < 4; c++)
            oacc[c] = mfma16(a, *(const half8*)(Wo + ((size_t)((s * 4 + c) * 64 + lane)) * 8), oacc[c]);
    }
    if (kh == 1)
        #pragma unroll
        for (int c = 0; c < 4; c++) pc[rt2][c][lane] = oacc[c];
    __syncthreads();
    if (kh == 0) {
        int mb2 = blockIdx.x * 32 + rt2 * 16;
        #pragma unroll
        for (int c = 0; c < 4; c++) {
            f32x4 p = pc[rt2][c][lane];
            int n = c * 16 + ln;
            if (n < OUT_) {
                float bv = bo[n];
                #pragma unroll
                for (int r = 0; r < 4; r++)
                    out[(size_t)(mb2 + quad * 4 + r) * OUT_ + n] = oacc[c][r] + p[r] + bv;
            }
        }
    }
}

extern "C" void kernel_launch(void* const* d_in, const int* in_sizes, int n_in,
                              void* d_out, int out_size, void* d_ws, size_t ws_size,
                              hipStream_t stream) {
    const float* x1    = (const float*)d_in[0];
    const float* x2    = (const float*)d_in[1];
    const float* ln1_g = (const float*)d_in[2];
    const float* ln1_b = (const float*)d_in[3];
    const float* ln2_g = (const float*)d_in[4];
    const float* ln2_b = (const float*)d_in[5];
    const float* Wq    = (const float*)d_in[6];
    const float* bq    = (const float*)d_in[7];
    const float* Wv1   = (const float*)d_in[8];
    const float* bv1   = (const float*)d_in[9];
    const float* Wk    = (const float*)d_in[10];
    const float* bk    = (const float*)d_in[11];
    const float* Wv2   = (const float*)d_in[12];
    const float* bv2   = (const float*)d_in[13];
    const float* Wp1   = (const float*)d_in[14];
    const float* bp1   = (const float*)d_in[15];
    const float* Wp2   = (const float*)d_in[16];
    const float* bp2   = (const float*)d_in[17];
    const float* lnf_g = (const float*)d_in[18];
    const float* lnf_b = (const float*)d_in[19];
    const float* Wf1   = (const float*)d_in[20];
    const float* bf1   = (const float*)d_in[21];
    const float* Wf2   = (const float*)d_in[22];
    const float* bf2   = (const float*)d_in[23];
    const float* ln3_g = (const float*)d_in[24];
    const float* ln3_b = (const float*)d_in[25];
    const float* Wo    = (const float*)d_in[26];
    const float* bo    = (const float*)d_in[27];
    float* out = (float*)d_out;

    char* ws = (char*)d_ws;
    const size_t MB = 1 << 20;
    _Float16* q1sw   = (_Float16*)(ws + 0 * MB);    // 4 MB
    _Float16* k2sw   = (_Float16*)(ws + 4 * MB);    // 4 MB
    unsigned char* vsw8 = (unsigned char*)(ws + 8 * MB);   // 4 MB (fp8 Vcat per batch)
    _Float16* att1   = (_Float16*)(ws + 12 * MB);   // 4 MB
    _Float16* att2   = (_Float16*)(ws + 16 * MB);   // 4 MB
    _Float16* wsw    = (_Float16*)(ws + 28 * MB);   // ~0.74 MB
    float*    rowsum = (float*)   (ws + 29 * MB);   // 64 KB
    _Float16* res    = (_Float16*)(ws + 30 * MB);   // 8 MB
    _Float16* xn     = (_Float16*)(ws + 46 * MB);   // 8 MB
    _Float16* h      = (_Float16*)(ws + 54 * MB);   // 16 MB
    unsigned char* pmat8 = (unsigned char*)(ws + 78 * MB); // 64 MB (fp8 P per batch)

    prep_kernel<<<dim3(512, 10), 256, 0, stream>>>(Wq, Wv1, Wk, Wv2, Wp1, Wp2, Wf1, Wf2, Wo,
                                                   wsw, rowsum);
    proj_kernel<<<dim3(M_ / 64, 2), 256, 0, stream>>>(x1, x2, wsw,
                                                      ln1_g, ln1_b, ln2_g, ln2_b,
                                                      bq, bv1, bk, bv2,
                                                      q1sw, k2sw, vsw8);
    score_kernel<<<dim3(32, 32, 4), 256, 0, stream>>>(q1sw, k2sw, pmat8, rowsum);
    pv_kernel<<<dim3(M_ / 32), 512, 0, stream>>>(pmat8, vsw8, rowsum, att1, att2);
    attn_out_kernel<<<dim3(M_ / 32), 256, 0, stream>>>(att1, att2, wsw, bp1, bp2,
                                                       x1, x2, lnf_g, lnf_b, res, xn);
    ffn1_kernel<<<dim3(M_ / 64, 4), 256, 0, stream>>>(xn, wsw, bf1, h);
    ffn2_out_kernel<<<dim3(M_ / 32), 256, 0, stream>>>(h, wsw, bf2, res, ln3_g, ln3_b, bo, out);
}